// Round 6
// baseline (1531.222 us; speedup 1.0000x reference)
//
#include <hip/hip_runtime.h>
#include <hip/hip_bf16.h>

// Nystromformer layer, MI355X. fp32 I/O, f16 MFMA internals, fp32 Newton-Schulz.
// R9: pinv chain at 2 launches/iter via {y2,u} / {z',y'} split (w2 formed in
//     B-staging; 3.25*E in epilogue); y0 = sc*a2@a2^T fused with z0 (no z0 dep);
//     conv fused into outh GEMM epilogue via LDS hs (k_h + outh buffer gone).
//     Dispatches: 32 (R8) -> 23.

typedef _Float16 f16;
typedef f16 f16x2 __attribute__((ext_vector_type(2)));
typedef f16 f16x4 __attribute__((ext_vector_type(4)));
typedef f16 f16x8 __attribute__((ext_vector_type(8)));
typedef float f32x4 __attribute__((ext_vector_type(4)));

__device__ __forceinline__ float waveMax(float v){
  #pragma unroll
  for(int i=32;i>0;i>>=1) v = fmaxf(v, __shfl_xor(v, i));
  return v;
}
__device__ __forceinline__ float waveSum(float v){
  #pragma unroll
  for(int i=32;i>0;i>>=1) v += __shfl_xor(v, i);
  return v;
}
__device__ __forceinline__ float blockMaxF(float v, float* sm){
  v = waveMax(v);
  if((threadIdx.x&63)==0) sm[threadIdx.x>>6] = v;
  __syncthreads();
  v = fmaxf(fmaxf(sm[0],sm[1]), fmaxf(sm[2],sm[3]));
  __syncthreads();
  return v;
}
__device__ __forceinline__ float blockSumF(float v, float* sm){
  v = waveSum(v);
  if((threadIdx.x&63)==0) sm[threadIdx.x>>6] = v;
  __syncthreads();
  v = sm[0]+sm[1]+sm[2]+sm[3];
  __syncthreads();
  return v;
}

__device__ __forceinline__ void async_cp16(const f16* g, const f16* l){
  __builtin_amdgcn_global_load_lds((const __attribute__((address_space(1))) void*)g,
                                   (__attribute__((address_space(3))) void*)l, 16, 0, 0);
}

// ---------------- MFMA GEMM body: C[M][N] = A[M][K] * Bt[N][K]^T -------------
// 128x128 tile, BK=64, 4 waves, 16x16x32 f16 MFMA.
__device__ __forceinline__ void gemm_body(
    const f16* __restrict__ A, const f16* __restrict__ Bt, void* __restrict__ C, int cf16,
    int N, int K, int m0, int n0, int kt0, int ktn,
    const float* __restrict__ bias, const float* __restrict__ resid,
    f16* As, f16* Bs)
{
  int t = threadIdx.x;
  int w = t>>6, lane = t&63;
  int quad = lane>>4, l16 = lane&15;
  int wr = w>>1, wc = w&1;
  f32x4 acc[4][4] = {};
  for(int kt=kt0; kt<kt0+ktn; ++kt){
    #pragma unroll
    for(int i=0;i<4;++i){
      int G = (w<<8)+(i<<6)+lane;
      int row = G>>3, gs = G&7;
      int g = gs ^ (row&7);                       // XOR-swizzled granule
      int koff = (kt<<6)+(g<<3);
      async_cp16(A + (long)(m0+row)*K + koff, As + (((w<<8)+(i<<6))<<3));
      async_cp16(Bt + (long)(n0+row)*K + koff, Bs + (((w<<8)+(i<<6))<<3));
    }
    __syncthreads();
    #pragma unroll
    for(int kk=0; kk<2; ++kk){
      f16x8 af[4], bfr[4];
      int gb = (kk<<2) + quad;
      #pragma unroll
      for(int mi=0;mi<4;++mi){
        int row = (wr<<6)+(mi<<4)+l16;
        af[mi] = *(const f16x8*)(As + ((row<<6) + ((gb ^ (row&7))<<3)));
      }
      #pragma unroll
      for(int ni=0;ni<4;++ni){
        int row = (wc<<6)+(ni<<4)+l16;
        bfr[ni] = *(const f16x8*)(Bs + ((row<<6) + ((gb ^ (row&7))<<3)));
      }
      #pragma unroll
      for(int mi=0;mi<4;++mi){
        #pragma unroll
        for(int ni=0;ni<4;++ni)
          acc[mi][ni] = __builtin_amdgcn_mfma_f32_16x16x32_f16(af[mi], bfr[ni], acc[mi][ni], 0,0,0);
      }
    }
    __syncthreads();
  }
  #pragma unroll
  for(int mi=0;mi<4;++mi){
    int rowb = m0 + (wr<<6) + (mi<<4) + (quad<<2);
    #pragma unroll
    for(int ni=0;ni<4;++ni){
      int col = n0 + (wc<<6) + (ni<<4) + l16;
      if(col < N){
        #pragma unroll
        for(int r=0;r<4;++r){
          float v = acc[mi][ni][r];
          if(bias)  v += bias[col];
          if(resid) v += resid[(long)(rowb+r)*N + col];
          if(cf16) ((f16*)C)[(long)(rowb+r)*N + col] = (f16)v;
          else     ((float*)C)[(long)(rowb+r)*N + col] = v;
        }
      }
    }
  }
}

// ------- fp32 GEMM body, split-K x4, partial-slice I/O (pinv chain) ----------
// Block computes beta*(A@Bv) over K-slice [ks*64,ks*64+64) of 64x64 tile of
// batch b; stores to slice ks of D. Bv = sum(B slices) + cB2*sum(B2 slices)
// + diagB*I (the w2-in-staging trick). ks==0 adds alpha*sum(E slices) + diagv*I.
// A,E,B2 slice stride 262144; B,D slice stride 4*256*Ncols.
__device__ __forceinline__ void g256_body(const float* __restrict__ A, const float* __restrict__ B,
    const float* __restrict__ B2, float cB2, float diagB,
    const float* __restrict__ E, float* __restrict__ D, int Ncols, float beta, float alpha,
    int AS, int BS, int ES, int bx, int by, int b, int ks, float* At, float* Bss, float diagv)
{
  long aOff = (long)b*65536;
  long bBatch = 256L*Ncols, bSl = 4L*bBatch;
  long bOff = (long)b*bBatch;
  long dOff = (long)ks*bSl + bOff;
  int r0 = bx*64, c0 = by*64;
  int t = threadIdx.x, tr = t>>4, tc = t&15;
  int arow = t>>2, ac4 = t&3;
  int bk = t>>4, bn4 = t&15;
  float acc[4][4] = {};
  for(int k0=ks*64;k0<ks*64+64;k0+=16){
    const float* pa = A + aOff + (long)(r0+arow)*256 + k0 + ac4*4;
    float4 va = *(const float4*)pa;
    for(int s=1;s<AS;++s){ float4 w2 = *(const float4*)(pa + (long)s*262144);
      va.x+=w2.x; va.y+=w2.y; va.z+=w2.z; va.w+=w2.w; }
    At[(ac4*4+0)*72+arow]=va.x; At[(ac4*4+1)*72+arow]=va.y;
    At[(ac4*4+2)*72+arow]=va.z; At[(ac4*4+3)*72+arow]=va.w;
    const float* pb = B + bOff + (long)(k0+bk)*Ncols + c0 + bn4*4;
    float4 vb = *(const float4*)pb;
    for(int s=1;s<BS;++s){ float4 w2 = *(const float4*)(pb + (long)s*bSl);
      vb.x+=w2.x; vb.y+=w2.y; vb.z+=w2.z; vb.w+=w2.w; }
    if(B2){
      const float* pb2 = B2 + (long)b*65536 + (long)(k0+bk)*256 + c0 + bn4*4;
      float s2x=0.f,s2y=0.f,s2z=0.f,s2w=0.f;
      for(int s=0;s<4;++s){ float4 w2 = *(const float4*)(pb2 + (long)s*262144);
        s2x+=w2.x; s2y+=w2.y; s2z+=w2.z; s2w+=w2.w; }
      vb.x+=cB2*s2x; vb.y+=cB2*s2y; vb.z+=cB2*s2z; vb.w+=cB2*s2w;
    }
    if(diagB != 0.f){
      int kglob = k0 + bk, cbase = c0 + bn4*4;
      float* pv = &vb.x;
      if(kglob>=cbase && kglob<cbase+4) pv[kglob-cbase] += diagB;
    }
    *(float4*)&Bss[bk*72+bn4*4] = vb;
    __syncthreads();
    #pragma unroll
    for(int kk=0;kk<16;++kk){
      float4 a4 = *(const float4*)&At[kk*72+tr*4];
      float4 b4 = *(const float4*)&Bss[kk*72+tc*4];
      float av[4] = {a4.x,a4.y,a4.z,a4.w};
      float bv[4] = {b4.x,b4.y,b4.z,b4.w};
      #pragma unroll
      for(int i=0;i<4;++i){
        #pragma unroll
        for(int j=0;j<4;++j) acc[i][j] += av[i]*bv[j];
      }
    }
    __syncthreads();
  }
  #pragma unroll
  for(int i=0;i<4;++i){
    int row = r0 + tr*4 + i;
    #pragma unroll
    for(int j=0;j<4;++j){
      int col = c0 + tc*4 + j;
      float v = beta*acc[i][j];
      if(ks==0){
        if(ES>0){
          const float* pe = E + aOff + (long)row*256 + col;
          float e = pe[0];
          for(int s=1;s<ES;++s) e += pe[(long)s*262144];
          v += alpha*e;
        }
        if(row==col) v += diagv;
      }
      D[dOff + (long)row*Ncols + col] = v;
    }
  }
}

// ---- y0 = sc * a2 @ a2^T (B staged A-style from a2 rows; symmetric) ---------
__device__ __forceinline__ void g256_aat(const float* __restrict__ A, float* __restrict__ D,
    float sc, int bx, int by, int b, int ks, float* At, float* Bss)
{
  long aOff = (long)b*65536;
  long dOff = (long)ks*1048576 + (long)b*65536;
  int r0 = bx*64, c0 = by*64;
  int t = threadIdx.x, tr = t>>4, tc = t&15;
  int arow = t>>2, ac4 = t&3;
  float acc[4][4] = {};
  for(int k0=ks*64;k0<ks*64+64;k0+=16){
    float4 va = *(const float4*)(A + aOff + (long)(r0+arow)*256 + k0 + ac4*4);
    At[(ac4*4+0)*72+arow]=va.x; At[(ac4*4+1)*72+arow]=va.y;
    At[(ac4*4+2)*72+arow]=va.z; At[(ac4*4+3)*72+arow]=va.w;
    float4 vb = *(const float4*)(A + aOff + (long)(c0+arow)*256 + k0 + ac4*4);
    Bss[(ac4*4+0)*72+arow]=vb.x; Bss[(ac4*4+1)*72+arow]=vb.y;
    Bss[(ac4*4+2)*72+arow]=vb.z; Bss[(ac4*4+3)*72+arow]=vb.w;
    __syncthreads();
    #pragma unroll
    for(int kk=0;kk<16;++kk){
      float4 a4 = *(const float4*)&At[kk*72+tr*4];
      float4 b4 = *(const float4*)&Bss[kk*72+tc*4];
      float av[4] = {a4.x,a4.y,a4.z,a4.w};
      float bv[4] = {b4.x,b4.y,b4.z,b4.w};
      #pragma unroll
      for(int i=0;i<4;++i){
        #pragma unroll
        for(int j=0;j<4;++j) acc[i][j] += av[i]*bv[j];
      }
    }
    __syncthreads();
  }
  #pragma unroll
  for(int i=0;i<4;++i){
    int row = r0 + tr*4 + i;
    #pragma unroll
    for(int j=0;j<4;++j){
      int col = c0 + tc*4 + j;
      D[dOff + (long)row*256 + col] = sc*acc[i][j];
    }
  }
}

// ---------------- F1: LayerNorm + weight transposes + zero scratch -----------
__global__ __launch_bounds__(256) void k_ln_prep(const float* __restrict__ x, const float* __restrict__ g,
    const float* __restrict__ be, f16* __restrict__ xn, const float* __restrict__ wqkv,
    const float* __restrict__ wout, f16* __restrict__ wqkT, f16* __restrict__ woutT,
    float* __restrict__ rs, unsigned* __restrict__ csmax){
  __shared__ float sm[8];
  int blk = blockIdx.x; int t = threadIdx.x;
  if(blk < 16384){
    long row = blk;
    const float* xr = x + row*512;
    float v0 = xr[t], v1 = xr[t+256];
    float s = waveSum(v0+v1), ss = waveSum(v0*v0+v1*v1);
    if((t&63)==0){ sm[t>>6] = s; sm[(t>>6)+4] = ss; }
    __syncthreads();
    s = sm[0]+sm[1]+sm[2]+sm[3]; ss = sm[4]+sm[5]+sm[6]+sm[7];
    float mu = s*(1.f/512.f);
    float var = ss*(1.f/512.f) - mu*mu;
    float rstd = rsqrtf(var + 1e-5f);
    xn[row*512+t]     = (f16)((v0-mu)*rstd*g[t]     + be[t]);
    xn[row*512+t+256] = (f16)((v1-mu)*rstd*g[t+256] + be[t+256]);
  } else if(blk < 16896){
    int i = (blk-16384)*256 + t; int n = i>>9, k = i&511;
    wqkT[i] = (n<192) ? (f16)wqkv[k*192+n] : (f16)0.0f;
  } else if(blk < 17024){
    int i = (blk-16896)*256 + t; int n = i>>6, k = i&63;
    woutT[i] = (f16)wout[k*512+n];
  } else {
    rs[t]=0.f; rs[t+256]=0.f; rs[t+512]=0.f; rs[t+768]=0.f;
    if(t==0){ *csmax = 0u; }
  }
}

// ---------------- F2: qkv = xn @ wqkT^T --------------------------------------
__global__ __launch_bounds__(256) void k_qkv(const f16* __restrict__ xn, const f16* __restrict__ wqkT,
                                             float* __restrict__ qkv){
  __shared__ f16 As[8192];
  __shared__ f16 Bs[8192];
  int blk = blockIdx.x;                 // 256 = (128 m) x (2 n)
  int bx = blk&127, by = blk>>7;
  gemm_body(xn, wqkT, qkv, 0, 192, 512, bx*128, by*128, 0, 8, nullptr, nullptr, As, Bs);
}

// ---------------- F3: split + vT + landmarks (all read qkv) ------------------
__global__ __launch_bounds__(256) void k_splitvl(const float* __restrict__ qkv,
    f16* __restrict__ qf, f16* __restrict__ kf, float* __restrict__ vf,
    f16* __restrict__ vT, f16* __restrict__ ql, f16* __restrict__ kl){
  __shared__ float tile[64][65];
  int blk = blockIdx.x; int t = threadIdx.x;
  if(blk < 4096){
    long row = (long)blk*4 + (t>>6); int d = t&63;
    const float* p = qkv + row*192;
    qf[row*64+d] = (f16)(p[d]*0.125f);
    kf[row*64+d] = (f16)(p[d+64]);
    vf[row*64+d] = p[d+128];
  } else if(blk < 4352){
    int bidx = blk-4096; int b = bidx>>6, n0 = (bidx&63)*64;
    int c = t&63, r4 = t>>6;
    #pragma unroll
    for(int i=0;i<16;++i){ int r = i*4+r4;
      tile[r][c] = qkv[((long)(b*4096 + n0 + r))*192 + 128 + c]; }
    __syncthreads();
    #pragma unroll
    for(int i=0;i<16;++i){ int d = i*4+r4;
      vT[((long)(b*128 + d))*4096 + n0 + c] = (f16)tile[c][d]; }
  } else {
    int bidx = blk-4352;                 // 256 blocks
    int bm = bidx*4 + (t>>6); int d = t&63;   // bm in [0,1024)
    const float* p = qkv + (long)bm*16*192;
    float sq=0.f, sk=0.f;
    #pragma unroll
    for(int i=0;i<16;++i){ sq += p[i*192+d]; sk += p[i*192+64+d]; }
    ql[bm*64+d] = (f16)(sq*0.0625f*0.125f);
    kl[bm*64+d] = (f16)(sk*0.0625f);
  }
}

// ---------------- F4: sims s1 | s2 | s3 --------------------------------------
__global__ __launch_bounds__(256) void k_sims(const f16* __restrict__ qf, const f16* __restrict__ kf,
    const f16* __restrict__ ql, const f16* __restrict__ kl,
    float* __restrict__ s1, float* __restrict__ s2, float* __restrict__ s3){
  __shared__ f16 As[8192];
  __shared__ f16 Bs[8192];
  int blk = blockIdx.x;
  if(blk < 256){                        // s1 = q @ kl^T : [4096 x 256], K=64
    int bx = blk&31, by = (blk>>5)&1, b = blk>>6;
    gemm_body(qf + (long)b*262144, kl + (long)b*16384, s1 + (long)b*1048576, 0,
              256, 64, bx*128, by*128, 0, 1, nullptr, nullptr, As, Bs);
  } else if(blk < 272){                 // s2 = ql @ kl^T : [256 x 256], K=64
    int idx = blk-256;
    int bx = idx&1, by = (idx>>1)&1, b = idx>>2;
    gemm_body(ql + (long)b*16384, kl + (long)b*16384, s2 + (long)b*65536, 0,
              256, 64, bx*128, by*128, 0, 1, nullptr, nullptr, As, Bs);
  } else {                              // s3 = ql @ k^T : [256 x 4096], K=64
    int idx = blk-272;
    int bx = idx&1, by = (idx>>1)&31, b = idx>>6;
    gemm_body(ql + (long)b*16384, kf + (long)b*262144, s3 + (long)b*1048576, 0,
              4096, 64, bx*128, by*128, 0, 1, nullptr, nullptr, As, Bs);
  }
}

// ---------------- F5: softmax1 | softmax2 | softmax3 -------------------------
__global__ __launch_bounds__(256) void k_softmaxes(const float* __restrict__ s1, f16* __restrict__ a1,
    const float* __restrict__ s2, float* __restrict__ a2, float* __restrict__ rs, unsigned* __restrict__ csmax,
    const float* __restrict__ s3, f16* __restrict__ a3){
  __shared__ float sm[4];
  int blk = blockIdx.x; int t = threadIdx.x;
  if(blk < 4096){
    int w = t>>6, lane = t&63;
    long row = (long)blk*4 + w;
    float4 v = *(const float4*)(s1 + row*256 + lane*4);
    float m = waveMax(fmaxf(fmaxf(v.x,v.y),fmaxf(v.z,v.w)));
    float e0 = __expf(v.x-m), e1 = __expf(v.y-m), e2 = __expf(v.z-m), e3 = __expf(v.w-m);
    float inv = 1.f/waveSum(e0+e1+e2+e3);
    f16x4 o = {(f16)(e0*inv),(f16)(e1*inv),(f16)(e2*inv),(f16)(e3*inv)};
    *(f16x4*)(a1 + row*256 + lane*4) = o;
  } else if(blk < 5120){
    int row = blk-4096; int b = row>>8;
    float v = s2[row*256+t];
    float m = blockMaxF(v, sm);
    float e = __expf(v-m);
    float sum = blockSumF(e, sm);
    float p = e/sum;
    a2[(long)row*256+t] = p;
    atomicAdd(&rs[b*256+t], p);
    float rowsum = blockSumF(p, sm);
    if(t==0) atomicMax(csmax, __float_as_uint(rowsum));
  } else {
    long row = blk-5120;
    const float* p = s3 + row*4096;
    float4 v[4]; float m = -1e30f;
    #pragma unroll
    for(int i=0;i<4;++i){
      v[i] = *(const float4*)(p + (i*256+t)*4);
      m = fmaxf(m, fmaxf(fmaxf(v[i].x,v[i].y),fmaxf(v[i].z,v[i].w)));
    }
    m = blockMaxF(m, sm);
    float sum = 0.f;
    #pragma unroll
    for(int i=0;i<4;++i){
      v[i].x = __expf(v[i].x-m); v[i].y = __expf(v[i].y-m);
      v[i].z = __expf(v[i].z-m); v[i].w = __expf(v[i].w-m);
      sum += v[i].x+v[i].y+v[i].z+v[i].w;
    }
    float inv = 1.f/blockSumF(sum, sm);
    f16* o = a3 + row*4096;
    #pragma unroll
    for(int i=0;i<4;++i){
      f16x4 ov = {(f16)(v[i].x*inv),(f16)(v[i].y*inv),(f16)(v[i].z*inv),(f16)(v[i].w*inv)};
      *(f16x4*)(o + (i*256+t)*4) = ov;
    }
  }
}

// ---------------- F6: trA3 | a3v split-K x8 ----------------------------------
__global__ __launch_bounds__(256) void k_trA3_a3v(const f16* __restrict__ a3, f16* __restrict__ a3T,
    const f16* __restrict__ vT, float* __restrict__ a3vp){
  __shared__ f16 As[8192];
  __shared__ f16 Bs[8192];
  __shared__ f16 tile[64][74];
  int blk = blockIdx.x; int t = threadIdx.x;
  if(blk < 1024){
    int bx = blk&63, by = (blk>>6)&3, b = blk>>8;
    int n0 = bx*64, m0 = by*64;
    const f16* A = a3 + (long)b*1048576; f16* T = a3T + (long)b*1048576;
    int c = t&63, r4 = t>>6;
    #pragma unroll
    for(int i=0;i<16;++i){ int r = i*4+r4; tile[r][c] = A[(long)(m0+r)*4096 + n0 + c]; }
    __syncthreads();
    #pragma unroll
    for(int i=0;i<16;++i){ int nr = i*4+r4; T[(long)(n0+nr)*256 + m0 + c] = tile[c][nr]; }
  } else {
    int idx = blk-1024;                 // 64 blocks: (2 m) x (32 z)
    int bx = idx&1, zz = idx>>1;
    int b = zz>>3, ksl = zz&7;
    gemm_body(a3 + (long)b*1048576, vT + (long)b*524288,
              a3vp + (long)ksl*65536 + (long)b*16384, 0,
              64, 4096, bx*128, 0, ksl*8, 8, nullptr, nullptr, As, Bs);
  }
}

// ---------------- F7: z0 = sc*a2^T (64 blk) | y0 = sc*a2@a2^T (256 blk) ------
__global__ __launch_bounds__(256) void k_z0y0(const float* __restrict__ a2, const float* __restrict__ rs,
    const unsigned* __restrict__ csmax, float* __restrict__ zA, float* __restrict__ y0){
  __shared__ float sm4[4];
  __shared__ float At[1152];
  __shared__ float Bss[1152];
  __shared__ float tile[64][65];
  int blk = blockIdx.x; int t = threadIdx.x;
  float m = fmaxf(fmaxf(rs[t],rs[t+256]), fmaxf(rs[t+512],rs[t+768]));
  m = blockMaxF(m, sm4);
  float sc = 1.f/(__uint_as_float(*csmax)*m);
  if(blk < 64){
    int ix = blk&3, jy = (blk>>2)&3, b = blk>>4;
    int i0 = ix*64, j0 = jy*64;
    const float* A = a2 + (long)b*65536; float* Z = zA + (long)b*65536;
    int c = t&63, r4 = t>>6;
    #pragma unroll
    for(int i=0;i<16;++i){ int r = i*4+r4; tile[r][c] = A[(j0+r)*256 + i0 + c]; }
    __syncthreads();
    #pragma unroll
    for(int i=0;i<16;++i){ int r = i*4+r4; Z[(i0+r)*256 + j0 + c] = tile[c][r]*sc; }
  } else {
    int idx = blk-64;
    int bx = idx&3, by = (idx>>2)&3, b = (idx>>4)&3, ks = idx>>6;
    g256_aat(a2, y0, sc, bx, by, b, ks, At, Bss);
  }
}

// ---------------- pinv launch A: y2 = y@y | u = zc@y (grid 4,4,32) -----------
__global__ __launch_bounds__(256) void k_nsA(const float* __restrict__ zc, int zAS,
    const float* __restrict__ y, float* __restrict__ y2, float* __restrict__ u){
  __shared__ float At[1152];
  __shared__ float Bss[1152];
  int z = blockIdx.z;
  if(z < 16){
    int b = z&3, ks = z>>2;
    g256_body(y, y, nullptr, 0.f, 0.f, nullptr, y2, 256, 1.f, 0.f, 4, 4, 0,
              blockIdx.x, blockIdx.y, b, ks, At, Bss, 0.f);
  } else {
    int zz = z-16; int b = zz&3, ks = zz>>2;
    g256_body(zc, y, nullptr, 0.f, 0.f, nullptr, u, 256, 1.f, 0.f, zAS, 4, 0,
              blockIdx.x, blockIdx.y, b, ks, At, Bss, 0.f);
  }
}

// ---- pinv launch B: z' = 3.25 zc - 0.25 u@w2 | y' = 3.25 y - 0.25 y2@w2 -----
// w2 = sum(y2) - 7 sum(y) + 15I formed during B-staging.
__global__ __launch_bounds__(256) void k_nsB(const float* __restrict__ zc, int zAS,
    const float* __restrict__ y, const float* __restrict__ y2, const float* __restrict__ u,
    float* __restrict__ zn, float* __restrict__ yn){
  __shared__ float At[1152];
  __shared__ float Bss[1152];
  int z = blockIdx.z;
  if(z < 16){
    int b = z&3, ks = z>>2;
    g256_body(u, y2, y, -7.f, 15.f, zc, zn, 256, -0.25f, 3.25f, 4, 4, zAS,
              blockIdx.x, blockIdx.y, b, ks, At, Bss, 0.f);
  } else {
    int zz = z-16; int b = zz&3, ks = zz>>2;
    g256_body(y2, y2, y, -7.f, 15.f, y, yn, 256, -0.25f, 3.25f, 4, 4, 4,
              blockIdx.x, blockIdx.y, b, ks, At, Bss, 0.f);
  }
}

// ---------------- pinv tail: za3v GEMM (64 blk) | zb combine (128 blk) -------
__global__ __launch_bounds__(256) void k_tail(const float* __restrict__ zc, const float* __restrict__ a3vp,
    float* __restrict__ pW, f16* __restrict__ zb){
  __shared__ float At[1152];
  __shared__ float Bss[1152];
  int blk = blockIdx.x; int t = threadIdx.x;
  if(blk < 64){
    int zx = blk&3, zz = blk>>2;
    int b = zz&3, ks = zz>>2;
    g256_body(zc, a3vp, nullptr, 0.f, 0.f, nullptr, pW, 64, 1.f, 0.f, 4, 8, 0,
              zx, 0, b, ks, At, Bss, 0.f);
  } else if(blk < 192){
    int base = (blk-64)*2048;
    #pragma unroll
    for(int k=0;k<8;++k){
      int i = base + k*256 + t;
      float v = zc[i] + zc[i+262144] + zc[i+524288] + zc[i+786432];
      zb[i] = (f16)v;
    }
  }
}

// ---- pW partials (4 slices of [4][256][64]) -> zaT f16 [4][128pad][256] -----
__global__ __launch_bounds__(256) void k_trZ(const float* __restrict__ pW, f16* __restrict__ zaT){
  int i = blockIdx.x*256 + threadIdx.x;   // 131072
  int b = i>>15, j = i&32767; int d = j>>8, m = j&255;
  float v = 0.f;
  if(d<64){
    long base = (long)b*16384 + (long)m*64 + d;
    v = pW[base] + pW[base+65536] + pW[base+131072] + pW[base+196608];
  }
  zaT[i] = (f16)v;
}

// ---- F8: h = a1@zaT^T + conv(v) (f16 out, blk<128) | U = a3T@zb^T -----------
__global__ __launch_bounds__(256) void k_outh_U(const f16* __restrict__ a1, const f16* __restrict__ zaT,
    const float* __restrict__ vf, const float* __restrict__ wconv, f16* __restrict__ h,
    const f16* __restrict__ a3T, const f16* __restrict__ zb, f16* __restrict__ U){
  __shared__ f16 As[8192];
  __shared__ f16 Bs[8192];
  __shared__ float hs[8192];
  __shared__ float wc[33];
  int blk = blockIdx.x; int t = threadIdx.x;
  if(blk < 128){                        // h: [4096 x 64], K=256, + conv epilogue
    if(t<33) wc[t] = wconv[t];
    int bx = blk&31, b = blk>>5;
    int m0 = bx*128;
    // GEMM writes into LDS hs[128][64] (A pre-offset by m0 so rows are local)
    gemm_body(a1 + (long)b*1048576 + (long)m0*256, zaT + (long)b*32768, hs, 0,
              64, 256, 0, 0, 0, 4, nullptr, nullptr, As, Bs);
    __syncthreads();
    #pragma unroll
    for(int i=0;i<32;++i){
      int e = i*256+t; int d = e&63; int r = e>>6; int n = m0+r;
      float acc = hs[e];
      #pragma unroll
      for(int tau=0;tau<33;++tau){
        int nn = n + tau - 16;
        if(nn>=0 && nn<4096) acc += wc[tau]*vf[((long)b*4096+nn)*64 + d];
      }
      h[((long)b*4096+n)*64 + d] = (f16)acc;
    }
  } else {                              // U: [4096 x 256], K=256, f16 out
    int idx = blk-128;
    int bx = idx&31, by = (idx>>5)&1, b = idx>>6;
    gemm_body(a3T + (long)b*1048576, zb + (long)b*65536, U + (long)b*1048576, 1,
              256, 256, bx*128, by*128, 0, 4, nullptr, nullptr, As, Bs);
  }
}

// ---------------- F10: out0 = x + h@woutT^T + bout | attn = a1@U^T -----------
__global__ __launch_bounds__(256) void k_out_attn(const f16* __restrict__ h, const f16* __restrict__ woutT,
    const float* __restrict__ x, const float* __restrict__ bout, float* __restrict__ out0,
    const f16* __restrict__ a1, const f16* __restrict__ U, float* __restrict__ attn){
  __shared__ f16 As[8192];
  __shared__ f16 Bs[8192];
  int blk = blockIdx.x;
  if(blk < 512){                        // out0: [16384 x 512], K=64
    int bx = blk&127, by = blk>>7;
    gemm_body(h, woutT, out0, 0, 512, 64, bx*128, by*128, 0, 1, bout, x, As, Bs);
  } else {                              // attn: [4096 x 4096], K=256
    int idx = blk-512;
    int bx = idx&31, by = (idx>>5)&31, b = idx>>10;
    gemm_body(a1 + (long)b*1048576, U + (long)b*1048576, attn + (long)b*16777216, 0,
              4096, 256, bx*128, by*128, 0, 4, nullptr, nullptr, As, Bs);
  }
}

extern "C" void kernel_launch(void* const* d_in, const int* in_sizes, int n_in,
                              void* d_out, int out_size, void* d_ws, size_t ws_size,
                              hipStream_t stream) {
  (void)in_sizes; (void)n_in; (void)out_size; (void)ws_size;
  const float* x     = (const float*)d_in[0];
  const float* gamma = (const float*)d_in[1];
  const float* beta  = (const float*)d_in[2];
  const float* wqkv  = (const float*)d_in[3];
  const float* wout  = (const float*)d_in[4];
  const float* bout  = (const float*)d_in[5];
  const float* wconv = (const float*)d_in[6];

  char* ws = (char*)d_ws;
  f16*   xn   = (f16*)(ws + 0);
  float* s3   = (float*)(ws + 0);          // reuse after qkv gemm
  float* s1   = (float*)(ws + 16777216);
  f16*   a3T  = (f16*)(ws + 16777216);     // reuse after softmax1
  f16*   U    = (f16*)(ws + 25165824);
  float* qkv  = (float*)(ws + 33554432);
  f16*   a3   = (f16*)(ws + 33554432);     // reuse after split
  float* pY   = (float*)(ws + 33554432);   // y-pong: reuses dead a3/qkv region during pinv
  f16*   a1   = (f16*)(ws + 46137344);
  f16*   qf   = (f16*)(ws + 54525952);
  f16*   kf   = (f16*)(ws + 56623104);
  float* vf   = (float*)(ws + 58720256);
  f16*   vT   = (f16*)(ws + 62914560);
  f16*   wqkT = (f16*)(ws + 67108864);
  f16*   ql   = (f16*)(ws + 67371008);
  f16*   kl   = (f16*)(ws + 67502080);
  float* s2   = (float*)(ws + 67633152);
  float* a2   = (float*)(ws + 68681728);
  float* zA   = (float*)(ws + 69730304);   // combined z0 [4][256][256] (1 MB)
  f16*   zb   = (f16*)(ws + 74973184);
  float* rs   = (float*)(ws + 76021760);
  unsigned* csmax = (unsigned*)(ws + 76021760 + 4096);
  f16*   zaT  = (f16*)(ws + 76029952);     // [4][128][256] f16
  f16*   woutT= (f16*)(ws + 76292096);     // [512][64] f16
  f16*   h    = (f16*)(ws + 80551936);     // [16384][64] f16
  float* pXZ  = (float*)(ws + 82649088);   // 4 MB: y ping
  float* pT1  = (float*)(ws + 86843392);   // 4 MB: y2
  float* pT2  = (float*)(ws + 91037696);   // 4 MB: u
  float* pU0  = (float*)(ws + 95232000);   // 4 MB: z ping
  float* pU1  = (float*)(ws + 99426304);   // 4 MB: z pong
  float* a3vp = (float*)(ws + 103620608);  // [8][4][256][64] fp32 = 2 MB
  float* pW   = (float*)(ws + 105717760);  // [4][4][256][64] fp32 = 1 MB

  float* out0 = (float*)d_out;
  float* attn = out0 + 8388608;

  k_ln_prep<<<17025,256,0,stream>>>(x, gamma, beta, xn, wqkv, wout, wqkT, woutT, rs, csmax);
  k_qkv<<<256,256,0,stream>>>(xn, wqkT, qkv);
  k_splitvl<<<4608,256,0,stream>>>(qkv, qf, kf, vf, vT, ql, kl);
  k_sims<<<528,256,0,stream>>>(qf, kf, ql, kl, s1, s2, s3);
  k_softmaxes<<<6144,256,0,stream>>>(s1, a1, s2, a2, rs, csmax, s3, a3);
  k_trA3_a3v<<<1088,256,0,stream>>>(a3, a3T, vT, a3vp);
  // z0 (64 blk) + y0 = sc*a2@a2^T (256 blk, 4 slices -> pXZ), one launch
  k_z0y0<<<320,256,0,stream>>>(a2, rs, csmax, zA, pXZ);

  // Newton-Schulz, 6 iterations, 2 launches each:
  //   A: y2 = y@y -> pT1 ; u = z@y -> pT2
  //   B: z' = 3.25 z - 0.25 u@w2 ; y' = 3.25 y - 0.25 y2@w2  (w2 staged)
  float* yb = pXZ;  float* yp = pY;
  const float* zc = zA; int zAS = 1;
  for(int it=0; it<6; ++it){
    k_nsA<<<dim3(4,4,32),256,0,stream>>>(zc, zAS, yb, pT1, pT2);
    float* zn = (it&1) ? pU1 : pU0;
    if(it < 5){
      k_nsB<<<dim3(4,4,32),256,0,stream>>>(zc, zAS, yb, pT1, pT2, zn, yp);
      float* tmp = yb; yb = yp; yp = tmp;
    } else {
      k_nsB<<<dim3(4,4,16),256,0,stream>>>(zc, zAS, yb, pT1, pT2, zn, yp);
    }
    zc = zn; zAS = 4;
  }
  // zc = final z (4 slices, pU1)
  k_tail<<<192,256,0,stream>>>(zc, a3vp, pW, zb);
  k_trZ<<<512,256,0,stream>>>(pW, zaT);

  k_outh_U<<<384,256,0,stream>>>(a1, zaT, vf, wconv, h, a3T, zb, U);
  k_out_attn<<<4608,256,0,stream>>>(h, woutT, x, bout, out0, a1, U, attn);
}

// Round 8
// 1173.190 us; speedup vs baseline: 1.3052x; 1.3052x over previous
//
#include <hip/hip_runtime.h>
#include <hip/hip_bf16.h>

// Nystromformer layer, MI355X. fp32 I/O, f16 MFMA internals, fp32 Newton-Schulz.
// R11 = R10 resubmitted unchanged (R10 bench was an infra failure: container
//       died twice, kernel never ran).
// R10 = R9 with g256_aat slice-stride bug fixed (ks*262144 elements, not
//       ks*1048576 which was the BYTE count and clobbered pT1/pT2/pU0).
// R9: pinv chain at 2 launches/iter via {y2,u} / {z',y'} split (w2 formed in
//     B-staging; 3.25*E in epilogue); y0 = sc*a2@a2^T fused with z0;
//     conv fused into outh GEMM epilogue via LDS hs. 23 dispatches.

typedef _Float16 f16;
typedef f16 f16x2 __attribute__((ext_vector_type(2)));
typedef f16 f16x4 __attribute__((ext_vector_type(4)));
typedef f16 f16x8 __attribute__((ext_vector_type(8)));
typedef float f32x4 __attribute__((ext_vector_type(4)));

__device__ __forceinline__ float waveMax(float v){
  #pragma unroll
  for(int i=32;i>0;i>>=1) v = fmaxf(v, __shfl_xor(v, i));
  return v;
}
__device__ __forceinline__ float waveSum(float v){
  #pragma unroll
  for(int i=32;i>0;i>>=1) v += __shfl_xor(v, i);
  return v;
}
__device__ __forceinline__ float blockMaxF(float v, float* sm){
  v = waveMax(v);
  if((threadIdx.x&63)==0) sm[threadIdx.x>>6] = v;
  __syncthreads();
  v = fmaxf(fmaxf(sm[0],sm[1]), fmaxf(sm[2],sm[3]));
  __syncthreads();
  return v;
}
__device__ __forceinline__ float blockSumF(float v, float* sm){
  v = waveSum(v);
  if((threadIdx.x&63)==0) sm[threadIdx.x>>6] = v;
  __syncthreads();
  v = sm[0]+sm[1]+sm[2]+sm[3];
  __syncthreads();
  return v;
}

__device__ __forceinline__ void async_cp16(const f16* g, const f16* l){
  __builtin_amdgcn_global_load_lds((const __attribute__((address_space(1))) void*)g,
                                   (__attribute__((address_space(3))) void*)l, 16, 0, 0);
}

// ---------------- MFMA GEMM body: C[M][N] = A[M][K] * Bt[N][K]^T -------------
// 128x128 tile, BK=64, 4 waves, 16x16x32 f16 MFMA.
__device__ __forceinline__ void gemm_body(
    const f16* __restrict__ A, const f16* __restrict__ Bt, void* __restrict__ C, int cf16,
    int N, int K, int m0, int n0, int kt0, int ktn,
    const float* __restrict__ bias, const float* __restrict__ resid,
    f16* As, f16* Bs)
{
  int t = threadIdx.x;
  int w = t>>6, lane = t&63;
  int quad = lane>>4, l16 = lane&15;
  int wr = w>>1, wc = w&1;
  f32x4 acc[4][4] = {};
  for(int kt=kt0; kt<kt0+ktn; ++kt){
    #pragma unroll
    for(int i=0;i<4;++i){
      int G = (w<<8)+(i<<6)+lane;
      int row = G>>3, gs = G&7;
      int g = gs ^ (row&7);                       // XOR-swizzled granule
      int koff = (kt<<6)+(g<<3);
      async_cp16(A + (long)(m0+row)*K + koff, As + (((w<<8)+(i<<6))<<3));
      async_cp16(Bt + (long)(n0+row)*K + koff, Bs + (((w<<8)+(i<<6))<<3));
    }
    __syncthreads();
    #pragma unroll
    for(int kk=0; kk<2; ++kk){
      f16x8 af[4], bfr[4];
      int gb = (kk<<2) + quad;
      #pragma unroll
      for(int mi=0;mi<4;++mi){
        int row = (wr<<6)+(mi<<4)+l16;
        af[mi] = *(const f16x8*)(As + ((row<<6) + ((gb ^ (row&7))<<3)));
      }
      #pragma unroll
      for(int ni=0;ni<4;++ni){
        int row = (wc<<6)+(ni<<4)+l16;
        bfr[ni] = *(const f16x8*)(Bs + ((row<<6) + ((gb ^ (row&7))<<3)));
      }
      #pragma unroll
      for(int mi=0;mi<4;++mi){
        #pragma unroll
        for(int ni=0;ni<4;++ni)
          acc[mi][ni] = __builtin_amdgcn_mfma_f32_16x16x32_f16(af[mi], bfr[ni], acc[mi][ni], 0,0,0);
      }
    }
    __syncthreads();
  }
  #pragma unroll
  for(int mi=0;mi<4;++mi){
    int rowb = m0 + (wr<<6) + (mi<<4) + (quad<<2);
    #pragma unroll
    for(int ni=0;ni<4;++ni){
      int col = n0 + (wc<<6) + (ni<<4) + l16;
      if(col < N){
        #pragma unroll
        for(int r=0;r<4;++r){
          float v = acc[mi][ni][r];
          if(bias)  v += bias[col];
          if(resid) v += resid[(long)(rowb+r)*N + col];
          if(cf16) ((f16*)C)[(long)(rowb+r)*N + col] = (f16)v;
          else     ((float*)C)[(long)(rowb+r)*N + col] = v;
        }
      }
    }
  }
}

// ------- fp32 GEMM body, split-K x4, partial-slice I/O (pinv chain) ----------
// Block computes beta*(A@Bv) over K-slice [ks*64,ks*64+64) of 64x64 tile of
// batch b; stores to slice ks of D. Bv = sum(B slices) + cB2*sum(B2 slices)
// + diagB*I (the w2-in-staging trick). ks==0 adds alpha*sum(E slices) + diagv*I.
// A,E,B2 slice stride 262144; B,D slice stride 4*256*Ncols.
__device__ __forceinline__ void g256_body(const float* __restrict__ A, const float* __restrict__ B,
    const float* __restrict__ B2, float cB2, float diagB,
    const float* __restrict__ E, float* __restrict__ D, int Ncols, float beta, float alpha,
    int AS, int BS, int ES, int bx, int by, int b, int ks, float* At, float* Bss, float diagv)
{
  long aOff = (long)b*65536;
  long bBatch = 256L*Ncols, bSl = 4L*bBatch;
  long bOff = (long)b*bBatch;
  long dOff = (long)ks*bSl + bOff;
  int r0 = bx*64, c0 = by*64;
  int t = threadIdx.x, tr = t>>4, tc = t&15;
  int arow = t>>2, ac4 = t&3;
  int bk = t>>4, bn4 = t&15;
  float acc[4][4] = {};
  for(int k0=ks*64;k0<ks*64+64;k0+=16){
    const float* pa = A + aOff + (long)(r0+arow)*256 + k0 + ac4*4;
    float4 va = *(const float4*)pa;
    for(int s=1;s<AS;++s){ float4 w2 = *(const float4*)(pa + (long)s*262144);
      va.x+=w2.x; va.y+=w2.y; va.z+=w2.z; va.w+=w2.w; }
    At[(ac4*4+0)*72+arow]=va.x; At[(ac4*4+1)*72+arow]=va.y;
    At[(ac4*4+2)*72+arow]=va.z; At[(ac4*4+3)*72+arow]=va.w;
    const float* pb = B + bOff + (long)(k0+bk)*Ncols + c0 + bn4*4;
    float4 vb = *(const float4*)pb;
    for(int s=1;s<BS;++s){ float4 w2 = *(const float4*)(pb + (long)s*bSl);
      vb.x+=w2.x; vb.y+=w2.y; vb.z+=w2.z; vb.w+=w2.w; }
    if(B2){
      const float* pb2 = B2 + (long)b*65536 + (long)(k0+bk)*256 + c0 + bn4*4;
      float s2x=0.f,s2y=0.f,s2z=0.f,s2w=0.f;
      for(int s=0;s<4;++s){ float4 w2 = *(const float4*)(pb2 + (long)s*262144);
        s2x+=w2.x; s2y+=w2.y; s2z+=w2.z; s2w+=w2.w; }
      vb.x+=cB2*s2x; vb.y+=cB2*s2y; vb.z+=cB2*s2z; vb.w+=cB2*s2w;
    }
    if(diagB != 0.f){
      int kglob = k0 + bk, cbase = c0 + bn4*4;
      float* pv = &vb.x;
      if(kglob>=cbase && kglob<cbase+4) pv[kglob-cbase] += diagB;
    }
    *(float4*)&Bss[bk*72+bn4*4] = vb;
    __syncthreads();
    #pragma unroll
    for(int kk=0;kk<16;++kk){
      float4 a4 = *(const float4*)&At[kk*72+tr*4];
      float4 b4 = *(const float4*)&Bss[kk*72+tc*4];
      float av[4] = {a4.x,a4.y,a4.z,a4.w};
      float bv[4] = {b4.x,b4.y,b4.z,b4.w};
      #pragma unroll
      for(int i=0;i<4;++i){
        #pragma unroll
        for(int j=0;j<4;++j) acc[i][j] += av[i]*bv[j];
      }
    }
    __syncthreads();
  }
  #pragma unroll
  for(int i=0;i<4;++i){
    int row = r0 + tr*4 + i;
    #pragma unroll
    for(int j=0;j<4;++j){
      int col = c0 + tc*4 + j;
      float v = beta*acc[i][j];
      if(ks==0){
        if(ES>0){
          const float* pe = E + aOff + (long)row*256 + col;
          float e = pe[0];
          for(int s=1;s<ES;++s) e += pe[(long)s*262144];
          v += alpha*e;
        }
        if(row==col) v += diagv;
      }
      D[dOff + (long)row*Ncols + col] = v;
    }
  }
}

// ---- y0 = sc * a2 @ a2^T (B staged A-style from a2 rows; symmetric) ---------
// Slice layout matches g256_body: slice stride 262144 ELEMENTS, batch 65536.
__device__ __forceinline__ void g256_aat(const float* __restrict__ A, float* __restrict__ D,
    float sc, int bx, int by, int b, int ks, float* At, float* Bss)
{
  long aOff = (long)b*65536;
  long dOff = (long)ks*262144 + (long)b*65536;   // R10 FIX (was ks*1048576)
  int r0 = bx*64, c0 = by*64;
  int t = threadIdx.x, tr = t>>4, tc = t&15;
  int arow = t>>2, ac4 = t&3;
  float acc[4][4] = {};
  for(int k0=ks*64;k0<ks*64+64;k0+=16){
    float4 va = *(const float4*)(A + aOff + (long)(r0+arow)*256 + k0 + ac4*4);
    At[(ac4*4+0)*72+arow]=va.x; At[(ac4*4+1)*72+arow]=va.y;
    At[(ac4*4+2)*72+arow]=va.z; At[(ac4*4+3)*72+arow]=va.w;
    float4 vb = *(const float4*)(A + aOff + (long)(c0+arow)*256 + k0 + ac4*4);
    Bss[(ac4*4+0)*72+arow]=vb.x; Bss[(ac4*4+1)*72+arow]=vb.y;
    Bss[(ac4*4+2)*72+arow]=vb.z; Bss[(ac4*4+3)*72+arow]=vb.w;
    __syncthreads();
    #pragma unroll
    for(int kk=0;kk<16;++kk){
      float4 a4 = *(const float4*)&At[kk*72+tr*4];
      float4 b4 = *(const float4*)&Bss[kk*72+tc*4];
      float av[4] = {a4.x,a4.y,a4.z,a4.w};
      float bv[4] = {b4.x,b4.y,b4.z,b4.w};
      #pragma unroll
      for(int i=0;i<4;++i){
        #pragma unroll
        for(int j=0;j<4;++j) acc[i][j] += av[i]*bv[j];
      }
    }
    __syncthreads();
  }
  #pragma unroll
  for(int i=0;i<4;++i){
    int row = r0 + tr*4 + i;
    #pragma unroll
    for(int j=0;j<4;++j){
      int col = c0 + tc*4 + j;
      D[dOff + (long)row*256 + col] = sc*acc[i][j];
    }
  }
}

// ---------------- F1: LayerNorm + weight transposes + zero scratch -----------
__global__ __launch_bounds__(256) void k_ln_prep(const float* __restrict__ x, const float* __restrict__ g,
    const float* __restrict__ be, f16* __restrict__ xn, const float* __restrict__ wqkv,
    const float* __restrict__ wout, f16* __restrict__ wqkT, f16* __restrict__ woutT,
    float* __restrict__ rs, unsigned* __restrict__ csmax){
  __shared__ float sm[8];
  int blk = blockIdx.x; int t = threadIdx.x;
  if(blk < 16384){
    long row = blk;
    const float* xr = x + row*512;
    float v0 = xr[t], v1 = xr[t+256];
    float s = waveSum(v0+v1), ss = waveSum(v0*v0+v1*v1);
    if((t&63)==0){ sm[t>>6] = s; sm[(t>>6)+4] = ss; }
    __syncthreads();
    s = sm[0]+sm[1]+sm[2]+sm[3]; ss = sm[4]+sm[5]+sm[6]+sm[7];
    float mu = s*(1.f/512.f);
    float var = ss*(1.f/512.f) - mu*mu;
    float rstd = rsqrtf(var + 1e-5f);
    xn[row*512+t]     = (f16)((v0-mu)*rstd*g[t]     + be[t]);
    xn[row*512+t+256] = (f16)((v1-mu)*rstd*g[t+256] + be[t+256]);
  } else if(blk < 16896){
    int i = (blk-16384)*256 + t; int n = i>>9, k = i&511;
    wqkT[i] = (n<192) ? (f16)wqkv[k*192+n] : (f16)0.0f;
  } else if(blk < 17024){
    int i = (blk-16896)*256 + t; int n = i>>6, k = i&63;
    woutT[i] = (f16)wout[k*512+n];
  } else {
    rs[t]=0.f; rs[t+256]=0.f; rs[t+512]=0.f; rs[t+768]=0.f;
    if(t==0){ *csmax = 0u; }
  }
}

// ---------------- F2: qkv = xn @ wqkT^T --------------------------------------
__global__ __launch_bounds__(256) void k_qkv(const f16* __restrict__ xn, const f16* __restrict__ wqkT,
                                             float* __restrict__ qkv){
  __shared__ f16 As[8192];
  __shared__ f16 Bs[8192];
  int blk = blockIdx.x;                 // 256 = (128 m) x (2 n)
  int bx = blk&127, by = blk>>7;
  gemm_body(xn, wqkT, qkv, 0, 192, 512, bx*128, by*128, 0, 8, nullptr, nullptr, As, Bs);
}

// ---------------- F3: split + vT + landmarks (all read qkv) ------------------
__global__ __launch_bounds__(256) void k_splitvl(const float* __restrict__ qkv,
    f16* __restrict__ qf, f16* __restrict__ kf, float* __restrict__ vf,
    f16* __restrict__ vT, f16* __restrict__ ql, f16* __restrict__ kl){
  __shared__ float tile[64][65];
  int blk = blockIdx.x; int t = threadIdx.x;
  if(blk < 4096){
    long row = (long)blk*4 + (t>>6); int d = t&63;
    const float* p = qkv + row*192;
    qf[row*64+d] = (f16)(p[d]*0.125f);
    kf[row*64+d] = (f16)(p[d+64]);
    vf[row*64+d] = p[d+128];
  } else if(blk < 4352){
    int bidx = blk-4096; int b = bidx>>6, n0 = (bidx&63)*64;
    int c = t&63, r4 = t>>6;
    #pragma unroll
    for(int i=0;i<16;++i){ int r = i*4+r4;
      tile[r][c] = qkv[((long)(b*4096 + n0 + r))*192 + 128 + c]; }
    __syncthreads();
    #pragma unroll
    for(int i=0;i<16;++i){ int d = i*4+r4;
      vT[((long)(b*128 + d))*4096 + n0 + c] = (f16)tile[c][d]; }
  } else {
    int bidx = blk-4352;                 // 256 blocks
    int bm = bidx*4 + (t>>6); int d = t&63;   // bm in [0,1024)
    const float* p = qkv + (long)bm*16*192;
    float sq=0.f, sk=0.f;
    #pragma unroll
    for(int i=0;i<16;++i){ sq += p[i*192+d]; sk += p[i*192+64+d]; }
    ql[bm*64+d] = (f16)(sq*0.0625f*0.125f);
    kl[bm*64+d] = (f16)(sk*0.0625f);
  }
}

// ---------------- F4: sims s1 | s2 | s3 --------------------------------------
__global__ __launch_bounds__(256) void k_sims(const f16* __restrict__ qf, const f16* __restrict__ kf,
    const f16* __restrict__ ql, const f16* __restrict__ kl,
    float* __restrict__ s1, float* __restrict__ s2, float* __restrict__ s3){
  __shared__ f16 As[8192];
  __shared__ f16 Bs[8192];
  int blk = blockIdx.x;
  if(blk < 256){                        // s1 = q @ kl^T : [4096 x 256], K=64
    int bx = blk&31, by = (blk>>5)&1, b = blk>>6;
    gemm_body(qf + (long)b*262144, kl + (long)b*16384, s1 + (long)b*1048576, 0,
              256, 64, bx*128, by*128, 0, 1, nullptr, nullptr, As, Bs);
  } else if(blk < 272){                 // s2 = ql @ kl^T : [256 x 256], K=64
    int idx = blk-256;
    int bx = idx&1, by = (idx>>1)&1, b = idx>>2;
    gemm_body(ql + (long)b*16384, kl + (long)b*16384, s2 + (long)b*65536, 0,
              256, 64, bx*128, by*128, 0, 1, nullptr, nullptr, As, Bs);
  } else {                              // s3 = ql @ k^T : [256 x 4096], K=64
    int idx = blk-272;
    int bx = idx&1, by = (idx>>1)&31, b = idx>>6;
    gemm_body(ql + (long)b*16384, kf + (long)b*262144, s3 + (long)b*1048576, 0,
              4096, 64, bx*128, by*128, 0, 1, nullptr, nullptr, As, Bs);
  }
}

// ---------------- F5: softmax1 | softmax2 | softmax3 -------------------------
__global__ __launch_bounds__(256) void k_softmaxes(const float* __restrict__ s1, f16* __restrict__ a1,
    const float* __restrict__ s2, float* __restrict__ a2, float* __restrict__ rs, unsigned* __restrict__ csmax,
    const float* __restrict__ s3, f16* __restrict__ a3){
  __shared__ float sm[4];
  int blk = blockIdx.x; int t = threadIdx.x;
  if(blk < 4096){
    int w = t>>6, lane = t&63;
    long row = (long)blk*4 + w;
    float4 v = *(const float4*)(s1 + row*256 + lane*4);
    float m = waveMax(fmaxf(fmaxf(v.x,v.y),fmaxf(v.z,v.w)));
    float e0 = __expf(v.x-m), e1 = __expf(v.y-m), e2 = __expf(v.z-m), e3 = __expf(v.w-m);
    float inv = 1.f/waveSum(e0+e1+e2+e3);
    f16x4 o = {(f16)(e0*inv),(f16)(e1*inv),(f16)(e2*inv),(f16)(e3*inv)};
    *(f16x4*)(a1 + row*256 + lane*4) = o;
  } else if(blk < 5120){
    int row = blk-4096; int b = row>>8;
    float v = s2[row*256+t];
    float m = blockMaxF(v, sm);
    float e = __expf(v-m);
    float sum = blockSumF(e, sm);
    float p = e/sum;
    a2[(long)row*256+t] = p;
    atomicAdd(&rs[b*256+t], p);
    float rowsum = blockSumF(p, sm);
    if(t==0) atomicMax(csmax, __float_as_uint(rowsum));
  } else {
    long row = blk-5120;
    const float* p = s3 + row*4096;
    float4 v[4]; float m = -1e30f;
    #pragma unroll
    for(int i=0;i<4;++i){
      v[i] = *(const float4*)(p + (i*256+t)*4);
      m = fmaxf(m, fmaxf(fmaxf(v[i].x,v[i].y),fmaxf(v[i].z,v[i].w)));
    }
    m = blockMaxF(m, sm);
    float sum = 0.f;
    #pragma unroll
    for(int i=0;i<4;++i){
      v[i].x = __expf(v[i].x-m); v[i].y = __expf(v[i].y-m);
      v[i].z = __expf(v[i].z-m); v[i].w = __expf(v[i].w-m);
      sum += v[i].x+v[i].y+v[i].z+v[i].w;
    }
    float inv = 1.f/blockSumF(sum, sm);
    f16* o = a3 + row*4096;
    #pragma unroll
    for(int i=0;i<4;++i){
      f16x4 ov = {(f16)(v[i].x*inv),(f16)(v[i].y*inv),(f16)(v[i].z*inv),(f16)(v[i].w*inv)};
      *(f16x4*)(o + (i*256+t)*4) = ov;
    }
  }
}

// ---------------- F6: trA3 | a3v split-K x8 ----------------------------------
__global__ __launch_bounds__(256) void k_trA3_a3v(const f16* __restrict__ a3, f16* __restrict__ a3T,
    const f16* __restrict__ vT, float* __restrict__ a3vp){
  __shared__ f16 As[8192];
  __shared__ f16 Bs[8192];
  __shared__ f16 tile[64][74];
  int blk = blockIdx.x; int t = threadIdx.x;
  if(blk < 1024){
    int bx = blk&63, by = (blk>>6)&3, b = blk>>8;
    int n0 = bx*64, m0 = by*64;
    const f16* A = a3 + (long)b*1048576; f16* T = a3T + (long)b*1048576;
    int c = t&63, r4 = t>>6;
    #pragma unroll
    for(int i=0;i<16;++i){ int r = i*4+r4; tile[r][c] = A[(long)(m0+r)*4096 + n0 + c]; }
    __syncthreads();
    #pragma unroll
    for(int i=0;i<16;++i){ int nr = i*4+r4; T[(long)(n0+nr)*256 + m0 + c] = tile[c][nr]; }
  } else {
    int idx = blk-1024;                 // 64 blocks: (2 m) x (32 z)
    int bx = idx&1, zz = idx>>1;
    int b = zz>>3, ksl = zz&7;
    gemm_body(a3 + (long)b*1048576, vT + (long)b*524288,
              a3vp + (long)ksl*65536 + (long)b*16384, 0,
              64, 4096, bx*128, 0, ksl*8, 8, nullptr, nullptr, As, Bs);
  }
}

// ---------------- F7: z0 = sc*a2^T (64 blk) | y0 = sc*a2@a2^T (256 blk) ------
__global__ __launch_bounds__(256) void k_z0y0(const float* __restrict__ a2, const float* __restrict__ rs,
    const unsigned* __restrict__ csmax, float* __restrict__ zA, float* __restrict__ y0){
  __shared__ float sm4[4];
  __shared__ float At[1152];
  __shared__ float Bss[1152];
  __shared__ float tile[64][65];
  int blk = blockIdx.x; int t = threadIdx.x;
  float m = fmaxf(fmaxf(rs[t],rs[t+256]), fmaxf(rs[t+512],rs[t+768]));
  m = blockMaxF(m, sm4);
  float sc = 1.f/(__uint_as_float(*csmax)*m);
  if(blk < 64){
    int ix = blk&3, jy = (blk>>2)&3, b = blk>>4;
    int i0 = ix*64, j0 = jy*64;
    const float* A = a2 + (long)b*65536; float* Z = zA + (long)b*65536;
    int c = t&63, r4 = t>>6;
    #pragma unroll
    for(int i=0;i<16;++i){ int r = i*4+r4; tile[r][c] = A[(j0+r)*256 + i0 + c]; }
    __syncthreads();
    #pragma unroll
    for(int i=0;i<16;++i){ int r = i*4+r4; Z[(i0+r)*256 + j0 + c] = tile[c][r]*sc; }
  } else {
    int idx = blk-64;
    int bx = idx&3, by = (idx>>2)&3, b = (idx>>4)&3, ks = idx>>6;
    g256_aat(a2, y0, sc, bx, by, b, ks, At, Bss);
  }
}

// ---------------- pinv launch A: y2 = y@y | u = zc@y (grid 4,4,32) -----------
__global__ __launch_bounds__(256) void k_nsA(const float* __restrict__ zc, int zAS,
    const float* __restrict__ y, float* __restrict__ y2, float* __restrict__ u){
  __shared__ float At[1152];
  __shared__ float Bss[1152];
  int z = blockIdx.z;
  if(z < 16){
    int b = z&3, ks = z>>2;
    g256_body(y, y, nullptr, 0.f, 0.f, nullptr, y2, 256, 1.f, 0.f, 4, 4, 0,
              blockIdx.x, blockIdx.y, b, ks, At, Bss, 0.f);
  } else {
    int zz = z-16; int b = zz&3, ks = zz>>2;
    g256_body(zc, y, nullptr, 0.f, 0.f, nullptr, u, 256, 1.f, 0.f, zAS, 4, 0,
              blockIdx.x, blockIdx.y, b, ks, At, Bss, 0.f);
  }
}

// ---- pinv launch B: z' = 3.25 zc - 0.25 u@w2 | y' = 3.25 y - 0.25 y2@w2 -----
// w2 = sum(y2) - 7 sum(y) + 15I formed during B-staging.
__global__ __launch_bounds__(256) void k_nsB(const float* __restrict__ zc, int zAS,
    const float* __restrict__ y, const float* __restrict__ y2, const float* __restrict__ u,
    float* __restrict__ zn, float* __restrict__ yn){
  __shared__ float At[1152];
  __shared__ float Bss[1152];
  int z = blockIdx.z;
  if(z < 16){
    int b = z&3, ks = z>>2;
    g256_body(u, y2, y, -7.f, 15.f, zc, zn, 256, -0.25f, 3.25f, 4, 4, zAS,
              blockIdx.x, blockIdx.y, b, ks, At, Bss, 0.f);
  } else {
    int zz = z-16; int b = zz&3, ks = zz>>2;
    g256_body(y2, y2, y, -7.f, 15.f, y, yn, 256, -0.25f, 3.25f, 4, 4, 4,
              blockIdx.x, blockIdx.y, b, ks, At, Bss, 0.f);
  }
}

// ---------------- pinv tail: za3v GEMM (64 blk) | zb combine (128 blk) -------
__global__ __launch_bounds__(256) void k_tail(const float* __restrict__ zc, const float* __restrict__ a3vp,
    float* __restrict__ pW, f16* __restrict__ zb){
  __shared__ float At[1152];
  __shared__ float Bss[1152];
  int blk = blockIdx.x; int t = threadIdx.x;
  if(blk < 64){
    int zx = blk&3, zz = blk>>2;
    int b = zz&3, ks = zz>>2;
    g256_body(zc, a3vp, nullptr, 0.f, 0.f, nullptr, pW, 64, 1.f, 0.f, 4, 8, 0,
              zx, 0, b, ks, At, Bss, 0.f);
  } else if(blk < 192){
    int base = (blk-64)*2048;
    #pragma unroll
    for(int k=0;k<8;++k){
      int i = base + k*256 + t;
      float v = zc[i] + zc[i+262144] + zc[i+524288] + zc[i+786432];
      zb[i] = (f16)v;
    }
  }
}

// ---- pW partials (4 slices of [4][256][64]) -> zaT f16 [4][128pad][256] -----
__global__ __launch_bounds__(256) void k_trZ(const float* __restrict__ pW, f16* __restrict__ zaT){
  int i = blockIdx.x*256 + threadIdx.x;   // 131072
  int b = i>>15, j = i&32767; int d = j>>8, m = j&255;
  float v = 0.f;
  if(d<64){
    long base = (long)b*16384 + (long)m*64 + d;
    v = pW[base] + pW[base+65536] + pW[base+131072] + pW[base+196608];
  }
  zaT[i] = (f16)v;
}

// ---- F8: h = a1@zaT^T + conv(v) (f16 out, blk<128) | U = a3T@zb^T -----------
__global__ __launch_bounds__(256) void k_outh_U(const f16* __restrict__ a1, const f16* __restrict__ zaT,
    const float* __restrict__ vf, const float* __restrict__ wconv, f16* __restrict__ h,
    const f16* __restrict__ a3T, const f16* __restrict__ zb, f16* __restrict__ U){
  __shared__ f16 As[8192];
  __shared__ f16 Bs[8192];
  __shared__ float hs[8192];
  __shared__ float wc[33];
  int blk = blockIdx.x; int t = threadIdx.x;
  if(blk < 128){                        // h: [4096 x 64], K=256, + conv epilogue
    if(t<33) wc[t] = wconv[t];
    int bx = blk&31, b = blk>>5;
    int m0 = bx*128;
    // GEMM writes into LDS hs[128][64] (A pre-offset by m0 so rows are local)
    gemm_body(a1 + (long)b*1048576 + (long)m0*256, zaT + (long)b*32768, hs, 0,
              64, 256, 0, 0, 0, 4, nullptr, nullptr, As, Bs);
    __syncthreads();
    #pragma unroll
    for(int i=0;i<32;++i){
      int e = i*256+t; int d = e&63; int r = e>>6; int n = m0+r;
      float acc = hs[e];
      #pragma unroll
      for(int tau=0;tau<33;++tau){
        int nn = n + tau - 16;
        if(nn>=0 && nn<4096) acc += wc[tau]*vf[((long)b*4096+nn)*64 + d];
      }
      h[((long)b*4096+n)*64 + d] = (f16)acc;
    }
  } else {                              // U: [4096 x 256], K=256, f16 out
    int idx = blk-128;
    int bx = idx&31, by = (idx>>5)&1, b = idx>>6;
    gemm_body(a3T + (long)b*1048576, zb + (long)b*65536, U + (long)b*1048576, 1,
              256, 256, bx*128, by*128, 0, 4, nullptr, nullptr, As, Bs);
  }
}

// ---------------- F10: out0 = x + h@woutT^T + bout | attn = a1@U^T -----------
__global__ __launch_bounds__(256) void k_out_attn(const f16* __restrict__ h, const f16* __restrict__ woutT,
    const float* __restrict__ x, const float* __restrict__ bout, float* __restrict__ out0,
    const f16* __restrict__ a1, const f16* __restrict__ U, float* __restrict__ attn){
  __shared__ f16 As[8192];
  __shared__ f16 Bs[8192];
  int blk = blockIdx.x;
  if(blk < 512){                        // out0: [16384 x 512], K=64
    int bx = blk&127, by = blk>>7;
    gemm_body(h, woutT, out0, 0, 512, 64, bx*128, by*128, 0, 1, bout, x, As, Bs);
  } else {                              // attn: [4096 x 4096], K=256
    int idx = blk-512;
    int bx = idx&31, by = (idx>>5)&31, b = idx>>10;
    gemm_body(a1 + (long)b*1048576, U + (long)b*1048576, attn + (long)b*16777216, 0,
              4096, 256, bx*128, by*128, 0, 4, nullptr, nullptr, As, Bs);
  }
}

extern "C" void kernel_launch(void* const* d_in, const int* in_sizes, int n_in,
                              void* d_out, int out_size, void* d_ws, size_t ws_size,
                              hipStream_t stream) {
  (void)in_sizes; (void)n_in; (void)out_size; (void)ws_size;
  const float* x     = (const float*)d_in[0];
  const float* gamma = (const float*)d_in[1];
  const float* beta  = (const float*)d_in[2];
  const float* wqkv  = (const float*)d_in[3];
  const float* wout  = (const float*)d_in[4];
  const float* bout  = (const float*)d_in[5];
  const float* wconv = (const float*)d_in[6];

  char* ws = (char*)d_ws;
  f16*   xn   = (f16*)(ws + 0);
  float* s3   = (float*)(ws + 0);          // reuse after qkv gemm
  float* s1   = (float*)(ws + 16777216);
  f16*   a3T  = (f16*)(ws + 16777216);     // reuse after softmax1
  f16*   U    = (f16*)(ws + 25165824);
  float* qkv  = (float*)(ws + 33554432);
  f16*   a3   = (f16*)(ws + 33554432);     // reuse after split
  float* pY   = (float*)(ws + 33554432);   // y-pong: reuses dead a3/qkv region during pinv
  f16*   a1   = (f16*)(ws + 46137344);
  f16*   qf   = (f16*)(ws + 54525952);
  f16*   kf   = (f16*)(ws + 56623104);
  float* vf   = (float*)(ws + 58720256);
  f16*   vT   = (f16*)(ws + 62914560);
  f16*   wqkT = (f16*)(ws + 67108864);
  f16*   ql   = (f16*)(ws + 67371008);
  f16*   kl   = (f16*)(ws + 67502080);
  float* s2   = (float*)(ws + 67633152);
  float* a2   = (float*)(ws + 68681728);
  float* zA   = (float*)(ws + 69730304);   // combined z0 [4][256][256] (1 MB)
  f16*   zb   = (f16*)(ws + 74973184);
  float* rs   = (float*)(ws + 76021760);
  unsigned* csmax = (unsigned*)(ws + 76021760 + 4096);
  f16*   zaT  = (f16*)(ws + 76029952);     // [4][128][256] f16
  f16*   woutT= (f16*)(ws + 76292096);     // [512][64] f16
  f16*   h    = (f16*)(ws + 80551936);     // [16384][64] f16
  float* pXZ  = (float*)(ws + 82649088);   // 4 MB: y ping
  float* pT1  = (float*)(ws + 86843392);   // 4 MB: y2
  float* pT2  = (float*)(ws + 91037696);   // 4 MB: u
  float* pU0  = (float*)(ws + 95232000);   // 4 MB: z ping
  float* pU1  = (float*)(ws + 99426304);   // 4 MB: z pong
  float* a3vp = (float*)(ws + 103620608);  // [8][4][256][64] fp32 = 2 MB
  float* pW   = (float*)(ws + 105717760);  // [4][4][256][64] fp32 = 1 MB

  float* out0 = (float*)d_out;
  float* attn = out0 + 8388608;

  k_ln_prep<<<17025,256,0,stream>>>(x, gamma, beta, xn, wqkv, wout, wqkT, woutT, rs, csmax);
  k_qkv<<<256,256,0,stream>>>(xn, wqkT, qkv);
  k_splitvl<<<4608,256,0,stream>>>(qkv, qf, kf, vf, vT, ql, kl);
  k_sims<<<528,256,0,stream>>>(qf, kf, ql, kl, s1, s2, s3);
  k_softmaxes<<<6144,256,0,stream>>>(s1, a1, s2, a2, rs, csmax, s3, a3);
  k_trA3_a3v<<<1088,256,0,stream>>>(a3, a3T, vT, a3vp);
  // z0 (64 blk) + y0 = sc*a2@a2^T (256 blk, 4 slices -> pXZ), one launch
  k_z0y0<<<320,256,0,stream>>>(a2, rs, csmax, zA, pXZ);

  // Newton-Schulz, 6 iterations, 2 launches each:
  //   A: y2 = y@y -> pT1 ; u = z@y -> pT2
  //   B: z' = 3.25 z - 0.25 u@w2 ; y' = 3.25 y - 0.25 y2@w2  (w2 staged)
  float* yb = pXZ;  float* yp = pY;
  const float* zc = zA; int zAS = 1;
  for(int it=0; it<6; ++it){
    k_nsA<<<dim3(4,4,32),256,0,stream>>>(zc, zAS, yb, pT1, pT2);
    float* zn = (it&1) ? pU1 : pU0;
    if(it < 5){
      k_nsB<<<dim3(4,4,32),256,0,stream>>>(zc, zAS, yb, pT1, pT2, zn, yp);
      float* tmp = yb; yb = yp; yp = tmp;
    } else {
      k_nsB<<<dim3(4,4,16),256,0,stream>>>(zc, zAS, yb, pT1, pT2, zn, yp);
    }
    zc = zn; zAS = 4;
  }
  // zc = final z (4 slices, pU1)
  k_tail<<<192,256,0,stream>>>(zc, a3vp, pW, zb);
  k_trZ<<<512,256,0,stream>>>(pW, zaT);

  k_outh_U<<<384,256,0,stream>>>(a1, zaT, vf, wconv, h, a3T, zb, U);
  k_out_attn<<<4608,256,0,stream>>>(h, woutT, x, bout, out0, a1, U, attn);
}

// Round 9
// 1169.169 us; speedup vs baseline: 1.3097x; 1.0034x over previous
//
#include <hip/hip_runtime.h>
#include <hip/hip_bf16.h>

// Nystromformer layer, MI355X. fp32 I/O, f16 MFMA internals, fp32 Newton-Schulz.
// R12 = R11 byte-identical replication (R9/R11 both ran on cold/contended
//       nodes — preloaded:0, 340-800s npz pushes — measuring 1173-1531us vs
//       752-834us for identical big kernels on warm nodes. This round
//       disambiguates node-state from structure before further edits.)
// R10 = R9 with g256_aat slice-stride bug fixed (ks*262144 elements, not
//       ks*1048576 which was the BYTE count and clobbered pT1/pT2/pU0).
// R9: pinv chain at 2 launches/iter via {y2,u} / {z',y'} split (w2 formed in
//     B-staging; 3.25*E in epilogue); y0 = sc*a2@a2^T fused with z0;
//     conv fused into outh GEMM epilogue via LDS hs. 23 dispatches.

typedef _Float16 f16;
typedef f16 f16x2 __attribute__((ext_vector_type(2)));
typedef f16 f16x4 __attribute__((ext_vector_type(4)));
typedef f16 f16x8 __attribute__((ext_vector_type(8)));
typedef float f32x4 __attribute__((ext_vector_type(4)));

__device__ __forceinline__ float waveMax(float v){
  #pragma unroll
  for(int i=32;i>0;i>>=1) v = fmaxf(v, __shfl_xor(v, i));
  return v;
}
__device__ __forceinline__ float waveSum(float v){
  #pragma unroll
  for(int i=32;i>0;i>>=1) v += __shfl_xor(v, i);
  return v;
}
__device__ __forceinline__ float blockMaxF(float v, float* sm){
  v = waveMax(v);
  if((threadIdx.x&63)==0) sm[threadIdx.x>>6] = v;
  __syncthreads();
  v = fmaxf(fmaxf(sm[0],sm[1]), fmaxf(sm[2],sm[3]));
  __syncthreads();
  return v;
}
__device__ __forceinline__ float blockSumF(float v, float* sm){
  v = waveSum(v);
  if((threadIdx.x&63)==0) sm[threadIdx.x>>6] = v;
  __syncthreads();
  v = sm[0]+sm[1]+sm[2]+sm[3];
  __syncthreads();
  return v;
}

__device__ __forceinline__ void async_cp16(const f16* g, const f16* l){
  __builtin_amdgcn_global_load_lds((const __attribute__((address_space(1))) void*)g,
                                   (__attribute__((address_space(3))) void*)l, 16, 0, 0);
}

// ---------------- MFMA GEMM body: C[M][N] = A[M][K] * Bt[N][K]^T -------------
// 128x128 tile, BK=64, 4 waves, 16x16x32 f16 MFMA.
__device__ __forceinline__ void gemm_body(
    const f16* __restrict__ A, const f16* __restrict__ Bt, void* __restrict__ C, int cf16,
    int N, int K, int m0, int n0, int kt0, int ktn,
    const float* __restrict__ bias, const float* __restrict__ resid,
    f16* As, f16* Bs)
{
  int t = threadIdx.x;
  int w = t>>6, lane = t&63;
  int quad = lane>>4, l16 = lane&15;
  int wr = w>>1, wc = w&1;
  f32x4 acc[4][4] = {};
  for(int kt=kt0; kt<kt0+ktn; ++kt){
    #pragma unroll
    for(int i=0;i<4;++i){
      int G = (w<<8)+(i<<6)+lane;
      int row = G>>3, gs = G&7;
      int g = gs ^ (row&7);                       // XOR-swizzled granule
      int koff = (kt<<6)+(g<<3);
      async_cp16(A + (long)(m0+row)*K + koff, As + (((w<<8)+(i<<6))<<3));
      async_cp16(Bt + (long)(n0+row)*K + koff, Bs + (((w<<8)+(i<<6))<<3));
    }
    __syncthreads();
    #pragma unroll
    for(int kk=0; kk<2; ++kk){
      f16x8 af[4], bfr[4];
      int gb = (kk<<2) + quad;
      #pragma unroll
      for(int mi=0;mi<4;++mi){
        int row = (wr<<6)+(mi<<4)+l16;
        af[mi] = *(const f16x8*)(As + ((row<<6) + ((gb ^ (row&7))<<3)));
      }
      #pragma unroll
      for(int ni=0;ni<4;++ni){
        int row = (wc<<6)+(ni<<4)+l16;
        bfr[ni] = *(const f16x8*)(Bs + ((row<<6) + ((gb ^ (row&7))<<3)));
      }
      #pragma unroll
      for(int mi=0;mi<4;++mi){
        #pragma unroll
        for(int ni=0;ni<4;++ni)
          acc[mi][ni] = __builtin_amdgcn_mfma_f32_16x16x32_f16(af[mi], bfr[ni], acc[mi][ni], 0,0,0);
      }
    }
    __syncthreads();
  }
  #pragma unroll
  for(int mi=0;mi<4;++mi){
    int rowb = m0 + (wr<<6) + (mi<<4) + (quad<<2);
    #pragma unroll
    for(int ni=0;ni<4;++ni){
      int col = n0 + (wc<<6) + (ni<<4) + l16;
      if(col < N){
        #pragma unroll
        for(int r=0;r<4;++r){
          float v = acc[mi][ni][r];
          if(bias)  v += bias[col];
          if(resid) v += resid[(long)(rowb+r)*N + col];
          if(cf16) ((f16*)C)[(long)(rowb+r)*N + col] = (f16)v;
          else     ((float*)C)[(long)(rowb+r)*N + col] = v;
        }
      }
    }
  }
}

// ------- fp32 GEMM body, split-K x4, partial-slice I/O (pinv chain) ----------
// Block computes beta*(A@Bv) over K-slice [ks*64,ks*64+64) of 64x64 tile of
// batch b; stores to slice ks of D. Bv = sum(B slices) + cB2*sum(B2 slices)
// + diagB*I (the w2-in-staging trick). ks==0 adds alpha*sum(E slices) + diagv*I.
// A,E,B2 slice stride 262144; B,D slice stride 4*256*Ncols.
__device__ __forceinline__ void g256_body(const float* __restrict__ A, const float* __restrict__ B,
    const float* __restrict__ B2, float cB2, float diagB,
    const float* __restrict__ E, float* __restrict__ D, int Ncols, float beta, float alpha,
    int AS, int BS, int ES, int bx, int by, int b, int ks, float* At, float* Bss, float diagv)
{
  long aOff = (long)b*65536;
  long bBatch = 256L*Ncols, bSl = 4L*bBatch;
  long bOff = (long)b*bBatch;
  long dOff = (long)ks*bSl + bOff;
  int r0 = bx*64, c0 = by*64;
  int t = threadIdx.x, tr = t>>4, tc = t&15;
  int arow = t>>2, ac4 = t&3;
  int bk = t>>4, bn4 = t&15;
  float acc[4][4] = {};
  for(int k0=ks*64;k0<ks*64+64;k0+=16){
    const float* pa = A + aOff + (long)(r0+arow)*256 + k0 + ac4*4;
    float4 va = *(const float4*)pa;
    for(int s=1;s<AS;++s){ float4 w2 = *(const float4*)(pa + (long)s*262144);
      va.x+=w2.x; va.y+=w2.y; va.z+=w2.z; va.w+=w2.w; }
    At[(ac4*4+0)*72+arow]=va.x; At[(ac4*4+1)*72+arow]=va.y;
    At[(ac4*4+2)*72+arow]=va.z; At[(ac4*4+3)*72+arow]=va.w;
    const float* pb = B + bOff + (long)(k0+bk)*Ncols + c0 + bn4*4;
    float4 vb = *(const float4*)pb;
    for(int s=1;s<BS;++s){ float4 w2 = *(const float4*)(pb + (long)s*bSl);
      vb.x+=w2.x; vb.y+=w2.y; vb.z+=w2.z; vb.w+=w2.w; }
    if(B2){
      const float* pb2 = B2 + (long)b*65536 + (long)(k0+bk)*256 + c0 + bn4*4;
      float s2x=0.f,s2y=0.f,s2z=0.f,s2w=0.f;
      for(int s=0;s<4;++s){ float4 w2 = *(const float4*)(pb2 + (long)s*262144);
        s2x+=w2.x; s2y+=w2.y; s2z+=w2.z; s2w+=w2.w; }
      vb.x+=cB2*s2x; vb.y+=cB2*s2y; vb.z+=cB2*s2z; vb.w+=cB2*s2w;
    }
    if(diagB != 0.f){
      int kglob = k0 + bk, cbase = c0 + bn4*4;
      float* pv = &vb.x;
      if(kglob>=cbase && kglob<cbase+4) pv[kglob-cbase] += diagB;
    }
    *(float4*)&Bss[bk*72+bn4*4] = vb;
    __syncthreads();
    #pragma unroll
    for(int kk=0;kk<16;++kk){
      float4 a4 = *(const float4*)&At[kk*72+tr*4];
      float4 b4 = *(const float4*)&Bss[kk*72+tc*4];
      float av[4] = {a4.x,a4.y,a4.z,a4.w};
      float bv[4] = {b4.x,b4.y,b4.z,b4.w};
      #pragma unroll
      for(int i=0;i<4;++i){
        #pragma unroll
        for(int j=0;j<4;++j) acc[i][j] += av[i]*bv[j];
      }
    }
    __syncthreads();
  }
  #pragma unroll
  for(int i=0;i<4;++i){
    int row = r0 + tr*4 + i;
    #pragma unroll
    for(int j=0;j<4;++j){
      int col = c0 + tc*4 + j;
      float v = beta*acc[i][j];
      if(ks==0){
        if(ES>0){
          const float* pe = E + aOff + (long)row*256 + col;
          float e = pe[0];
          for(int s=1;s<ES;++s) e += pe[(long)s*262144];
          v += alpha*e;
        }
        if(row==col) v += diagv;
      }
      D[dOff + (long)row*Ncols + col] = v;
    }
  }
}

// ---- y0 = sc * a2 @ a2^T (B staged A-style from a2 rows; symmetric) ---------
// Slice layout matches g256_body: slice stride 262144 ELEMENTS, batch 65536.
__device__ __forceinline__ void g256_aat(const float* __restrict__ A, float* __restrict__ D,
    float sc, int bx, int by, int b, int ks, float* At, float* Bss)
{
  long aOff = (long)b*65536;
  long dOff = (long)ks*262144 + (long)b*65536;   // R10 FIX (was ks*1048576)
  int r0 = bx*64, c0 = by*64;
  int t = threadIdx.x, tr = t>>4, tc = t&15;
  int arow = t>>2, ac4 = t&3;
  float acc[4][4] = {};
  for(int k0=ks*64;k0<ks*64+64;k0+=16){
    float4 va = *(const float4*)(A + aOff + (long)(r0+arow)*256 + k0 + ac4*4);
    At[(ac4*4+0)*72+arow]=va.x; At[(ac4*4+1)*72+arow]=va.y;
    At[(ac4*4+2)*72+arow]=va.z; At[(ac4*4+3)*72+arow]=va.w;
    float4 vb = *(const float4*)(A + aOff + (long)(c0+arow)*256 + k0 + ac4*4);
    Bss[(ac4*4+0)*72+arow]=vb.x; Bss[(ac4*4+1)*72+arow]=vb.y;
    Bss[(ac4*4+2)*72+arow]=vb.z; Bss[(ac4*4+3)*72+arow]=vb.w;
    __syncthreads();
    #pragma unroll
    for(int kk=0;kk<16;++kk){
      float4 a4 = *(const float4*)&At[kk*72+tr*4];
      float4 b4 = *(const float4*)&Bss[kk*72+tc*4];
      float av[4] = {a4.x,a4.y,a4.z,a4.w};
      float bv[4] = {b4.x,b4.y,b4.z,b4.w};
      #pragma unroll
      for(int i=0;i<4;++i){
        #pragma unroll
        for(int j=0;j<4;++j) acc[i][j] += av[i]*bv[j];
      }
    }
    __syncthreads();
  }
  #pragma unroll
  for(int i=0;i<4;++i){
    int row = r0 + tr*4 + i;
    #pragma unroll
    for(int j=0;j<4;++j){
      int col = c0 + tc*4 + j;
      D[dOff + (long)row*256 + col] = sc*acc[i][j];
    }
  }
}

// ---------------- F1: LayerNorm + weight transposes + zero scratch -----------
__global__ __launch_bounds__(256) void k_ln_prep(const float* __restrict__ x, const float* __restrict__ g,
    const float* __restrict__ be, f16* __restrict__ xn, const float* __restrict__ wqkv,
    const float* __restrict__ wout, f16* __restrict__ wqkT, f16* __restrict__ woutT,
    float* __restrict__ rs, unsigned* __restrict__ csmax){
  __shared__ float sm[8];
  int blk = blockIdx.x; int t = threadIdx.x;
  if(blk < 16384){
    long row = blk;
    const float* xr = x + row*512;
    float v0 = xr[t], v1 = xr[t+256];
    float s = waveSum(v0+v1), ss = waveSum(v0*v0+v1*v1);
    if((t&63)==0){ sm[t>>6] = s; sm[(t>>6)+4] = ss; }
    __syncthreads();
    s = sm[0]+sm[1]+sm[2]+sm[3]; ss = sm[4]+sm[5]+sm[6]+sm[7];
    float mu = s*(1.f/512.f);
    float var = ss*(1.f/512.f) - mu*mu;
    float rstd = rsqrtf(var + 1e-5f);
    xn[row*512+t]     = (f16)((v0-mu)*rstd*g[t]     + be[t]);
    xn[row*512+t+256] = (f16)((v1-mu)*rstd*g[t+256] + be[t+256]);
  } else if(blk < 16896){
    int i = (blk-16384)*256 + t; int n = i>>9, k = i&511;
    wqkT[i] = (n<192) ? (f16)wqkv[k*192+n] : (f16)0.0f;
  } else if(blk < 17024){
    int i = (blk-16896)*256 + t; int n = i>>6, k = i&63;
    woutT[i] = (f16)wout[k*512+n];
  } else {
    rs[t]=0.f; rs[t+256]=0.f; rs[t+512]=0.f; rs[t+768]=0.f;
    if(t==0){ *csmax = 0u; }
  }
}

// ---------------- F2: qkv = xn @ wqkT^T --------------------------------------
__global__ __launch_bounds__(256) void k_qkv(const f16* __restrict__ xn, const f16* __restrict__ wqkT,
                                             float* __restrict__ qkv){
  __shared__ f16 As[8192];
  __shared__ f16 Bs[8192];
  int blk = blockIdx.x;                 // 256 = (128 m) x (2 n)
  int bx = blk&127, by = blk>>7;
  gemm_body(xn, wqkT, qkv, 0, 192, 512, bx*128, by*128, 0, 8, nullptr, nullptr, As, Bs);
}

// ---------------- F3: split + vT + landmarks (all read qkv) ------------------
__global__ __launch_bounds__(256) void k_splitvl(const float* __restrict__ qkv,
    f16* __restrict__ qf, f16* __restrict__ kf, float* __restrict__ vf,
    f16* __restrict__ vT, f16* __restrict__ ql, f16* __restrict__ kl){
  __shared__ float tile[64][65];
  int blk = blockIdx.x; int t = threadIdx.x;
  if(blk < 4096){
    long row = (long)blk*4 + (t>>6); int d = t&63;
    const float* p = qkv + row*192;
    qf[row*64+d] = (f16)(p[d]*0.125f);
    kf[row*64+d] = (f16)(p[d+64]);
    vf[row*64+d] = p[d+128];
  } else if(blk < 4352){
    int bidx = blk-4096; int b = bidx>>6, n0 = (bidx&63)*64;
    int c = t&63, r4 = t>>6;
    #pragma unroll
    for(int i=0;i<16;++i){ int r = i*4+r4;
      tile[r][c] = qkv[((long)(b*4096 + n0 + r))*192 + 128 + c]; }
    __syncthreads();
    #pragma unroll
    for(int i=0;i<16;++i){ int d = i*4+r4;
      vT[((long)(b*128 + d))*4096 + n0 + c] = (f16)tile[c][d]; }
  } else {
    int bidx = blk-4352;                 // 256 blocks
    int bm = bidx*4 + (t>>6); int d = t&63;   // bm in [0,1024)
    const float* p = qkv + (long)bm*16*192;
    float sq=0.f, sk=0.f;
    #pragma unroll
    for(int i=0;i<16;++i){ sq += p[i*192+d]; sk += p[i*192+64+d]; }
    ql[bm*64+d] = (f16)(sq*0.0625f*0.125f);
    kl[bm*64+d] = (f16)(sk*0.0625f);
  }
}

// ---------------- F4: sims s1 | s2 | s3 --------------------------------------
__global__ __launch_bounds__(256) void k_sims(const f16* __restrict__ qf, const f16* __restrict__ kf,
    const f16* __restrict__ ql, const f16* __restrict__ kl,
    float* __restrict__ s1, float* __restrict__ s2, float* __restrict__ s3){
  __shared__ f16 As[8192];
  __shared__ f16 Bs[8192];
  int blk = blockIdx.x;
  if(blk < 256){                        // s1 = q @ kl^T : [4096 x 256], K=64
    int bx = blk&31, by = (blk>>5)&1, b = blk>>6;
    gemm_body(qf + (long)b*262144, kl + (long)b*16384, s1 + (long)b*1048576, 0,
              256, 64, bx*128, by*128, 0, 1, nullptr, nullptr, As, Bs);
  } else if(blk < 272){                 // s2 = ql @ kl^T : [256 x 256], K=64
    int idx = blk-256;
    int bx = idx&1, by = (idx>>1)&1, b = idx>>2;
    gemm_body(ql + (long)b*16384, kl + (long)b*16384, s2 + (long)b*65536, 0,
              256, 64, bx*128, by*128, 0, 1, nullptr, nullptr, As, Bs);
  } else {                              // s3 = ql @ k^T : [256 x 4096], K=64
    int idx = blk-272;
    int bx = idx&1, by = (idx>>1)&31, b = idx>>6;
    gemm_body(ql + (long)b*16384, kf + (long)b*262144, s3 + (long)b*1048576, 0,
              4096, 64, bx*128, by*128, 0, 1, nullptr, nullptr, As, Bs);
  }
}

// ---------------- F5: softmax1 | softmax2 | softmax3 -------------------------
__global__ __launch_bounds__(256) void k_softmaxes(const float* __restrict__ s1, f16* __restrict__ a1,
    const float* __restrict__ s2, float* __restrict__ a2, float* __restrict__ rs, unsigned* __restrict__ csmax,
    const float* __restrict__ s3, f16* __restrict__ a3){
  __shared__ float sm[4];
  int blk = blockIdx.x; int t = threadIdx.x;
  if(blk < 4096){
    int w = t>>6, lane = t&63;
    long row = (long)blk*4 + w;
    float4 v = *(const float4*)(s1 + row*256 + lane*4);
    float m = waveMax(fmaxf(fmaxf(v.x,v.y),fmaxf(v.z,v.w)));
    float e0 = __expf(v.x-m), e1 = __expf(v.y-m), e2 = __expf(v.z-m), e3 = __expf(v.w-m);
    float inv = 1.f/waveSum(e0+e1+e2+e3);
    f16x4 o = {(f16)(e0*inv),(f16)(e1*inv),(f16)(e2*inv),(f16)(e3*inv)};
    *(f16x4*)(a1 + row*256 + lane*4) = o;
  } else if(blk < 5120){
    int row = blk-4096; int b = row>>8;
    float v = s2[row*256+t];
    float m = blockMaxF(v, sm);
    float e = __expf(v-m);
    float sum = blockSumF(e, sm);
    float p = e/sum;
    a2[(long)row*256+t] = p;
    atomicAdd(&rs[b*256+t], p);
    float rowsum = blockSumF(p, sm);
    if(t==0) atomicMax(csmax, __float_as_uint(rowsum));
  } else {
    long row = blk-5120;
    const float* p = s3 + row*4096;
    float4 v[4]; float m = -1e30f;
    #pragma unroll
    for(int i=0;i<4;++i){
      v[i] = *(const float4*)(p + (i*256+t)*4);
      m = fmaxf(m, fmaxf(fmaxf(v[i].x,v[i].y),fmaxf(v[i].z,v[i].w)));
    }
    m = blockMaxF(m, sm);
    float sum = 0.f;
    #pragma unroll
    for(int i=0;i<4;++i){
      v[i].x = __expf(v[i].x-m); v[i].y = __expf(v[i].y-m);
      v[i].z = __expf(v[i].z-m); v[i].w = __expf(v[i].w-m);
      sum += v[i].x+v[i].y+v[i].z+v[i].w;
    }
    float inv = 1.f/blockSumF(sum, sm);
    f16* o = a3 + row*4096;
    #pragma unroll
    for(int i=0;i<4;++i){
      f16x4 ov = {(f16)(v[i].x*inv),(f16)(v[i].y*inv),(f16)(v[i].z*inv),(f16)(v[i].w*inv)};
      *(f16x4*)(o + (i*256+t)*4) = ov;
    }
  }
}

// ---------------- F6: trA3 | a3v split-K x8 ----------------------------------
__global__ __launch_bounds__(256) void k_trA3_a3v(const f16* __restrict__ a3, f16* __restrict__ a3T,
    const f16* __restrict__ vT, float* __restrict__ a3vp){
  __shared__ f16 As[8192];
  __shared__ f16 Bs[8192];
  __shared__ f16 tile[64][74];
  int blk = blockIdx.x; int t = threadIdx.x;
  if(blk < 1024){
    int bx = blk&63, by = (blk>>6)&3, b = blk>>8;
    int n0 = bx*64, m0 = by*64;
    const f16* A = a3 + (long)b*1048576; f16* T = a3T + (long)b*1048576;
    int c = t&63, r4 = t>>6;
    #pragma unroll
    for(int i=0;i<16;++i){ int r = i*4+r4; tile[r][c] = A[(long)(m0+r)*4096 + n0 + c]; }
    __syncthreads();
    #pragma unroll
    for(int i=0;i<16;++i){ int nr = i*4+r4; T[(long)(n0+nr)*256 + m0 + c] = tile[c][nr]; }
  } else {
    int idx = blk-1024;                 // 64 blocks: (2 m) x (32 z)
    int bx = idx&1, zz = idx>>1;
    int b = zz>>3, ksl = zz&7;
    gemm_body(a3 + (long)b*1048576, vT + (long)b*524288,
              a3vp + (long)ksl*65536 + (long)b*16384, 0,
              64, 4096, bx*128, 0, ksl*8, 8, nullptr, nullptr, As, Bs);
  }
}

// ---------------- F7: z0 = sc*a2^T (64 blk) | y0 = sc*a2@a2^T (256 blk) ------
__global__ __launch_bounds__(256) void k_z0y0(const float* __restrict__ a2, const float* __restrict__ rs,
    const unsigned* __restrict__ csmax, float* __restrict__ zA, float* __restrict__ y0){
  __shared__ float sm4[4];
  __shared__ float At[1152];
  __shared__ float Bss[1152];
  __shared__ float tile[64][65];
  int blk = blockIdx.x; int t = threadIdx.x;
  float m = fmaxf(fmaxf(rs[t],rs[t+256]), fmaxf(rs[t+512],rs[t+768]));
  m = blockMaxF(m, sm4);
  float sc = 1.f/(__uint_as_float(*csmax)*m);
  if(blk < 64){
    int ix = blk&3, jy = (blk>>2)&3, b = blk>>4;
    int i0 = ix*64, j0 = jy*64;
    const float* A = a2 + (long)b*65536; float* Z = zA + (long)b*65536;
    int c = t&63, r4 = t>>6;
    #pragma unroll
    for(int i=0;i<16;++i){ int r = i*4+r4; tile[r*65+c>=0?r:0][c] = A[(j0+r)*256 + i0 + c]; }
    __syncthreads();
    #pragma unroll
    for(int i=0;i<16;++i){ int r = i*4+r4; Z[(i0+r)*256 + j0 + c] = tile[c][r]*sc; }
  } else {
    int idx = blk-64;
    int bx = idx&3, by = (idx>>2)&3, b = (idx>>4)&3, ks = idx>>6;
    g256_aat(a2, y0, sc, bx, by, b, ks, At, Bss);
  }
}

// ---------------- pinv launch A: y2 = y@y | u = zc@y (grid 4,4,32) -----------
__global__ __launch_bounds__(256) void k_nsA(const float* __restrict__ zc, int zAS,
    const float* __restrict__ y, float* __restrict__ y2, float* __restrict__ u){
  __shared__ float At[1152];
  __shared__ float Bss[1152];
  int z = blockIdx.z;
  if(z < 16){
    int b = z&3, ks = z>>2;
    g256_body(y, y, nullptr, 0.f, 0.f, nullptr, y2, 256, 1.f, 0.f, 4, 4, 0,
              blockIdx.x, blockIdx.y, b, ks, At, Bss, 0.f);
  } else {
    int zz = z-16; int b = zz&3, ks = zz>>2;
    g256_body(zc, y, nullptr, 0.f, 0.f, nullptr, u, 256, 1.f, 0.f, zAS, 4, 0,
              blockIdx.x, blockIdx.y, b, ks, At, Bss, 0.f);
  }
}

// ---- pinv launch B: z' = 3.25 zc - 0.25 u@w2 | y' = 3.25 y - 0.25 y2@w2 -----
// w2 = sum(y2) - 7 sum(y) + 15I formed during B-staging.
__global__ __launch_bounds__(256) void k_nsB(const float* __restrict__ zc, int zAS,
    const float* __restrict__ y, const float* __restrict__ y2, const float* __restrict__ u,
    float* __restrict__ zn, float* __restrict__ yn){
  __shared__ float At[1152];
  __shared__ float Bss[1152];
  int z = blockIdx.z;
  if(z < 16){
    int b = z&3, ks = z>>2;
    g256_body(u, y2, y, -7.f, 15.f, zc, zn, 256, -0.25f, 3.25f, 4, 4, zAS,
              blockIdx.x, blockIdx.y, b, ks, At, Bss, 0.f);
  } else {
    int zz = z-16; int b = zz&3, ks = zz>>2;
    g256_body(y2, y2, y, -7.f, 15.f, y, yn, 256, -0.25f, 3.25f, 4, 4, 4,
              blockIdx.x, blockIdx.y, b, ks, At, Bss, 0.f);
  }
}

// ---------------- pinv tail: za3v GEMM (64 blk) | zb combine (128 blk) -------
__global__ __launch_bounds__(256) void k_tail(const float* __restrict__ zc, const float* __restrict__ a3vp,
    float* __restrict__ pW, f16* __restrict__ zb){
  __shared__ float At[1152];
  __shared__ float Bss[1152];
  int blk = blockIdx.x; int t = threadIdx.x;
  if(blk < 64){
    int zx = blk&3, zz = blk>>2;
    int b = zz&3, ks = zz>>2;
    g256_body(zc, a3vp, nullptr, 0.f, 0.f, nullptr, pW, 64, 1.f, 0.f, 4, 8, 0,
              zx, 0, b, ks, At, Bss, 0.f);
  } else if(blk < 192){
    int base = (blk-64)*2048;
    #pragma unroll
    for(int k=0;k<8;++k){
      int i = base + k*256 + t;
      float v = zc[i] + zc[i+262144] + zc[i+524288] + zc[i+786432];
      zb[i] = (f16)v;
    }
  }
}

// ---- pW partials (4 slices of [4][256][64]) -> zaT f16 [4][128pad][256] -----
__global__ __launch_bounds__(256) void k_trZ(const float* __restrict__ pW, f16* __restrict__ zaT){
  int i = blockIdx.x*256 + threadIdx.x;   // 131072
  int b = i>>15, j = i&32767; int d = j>>8, m = j&255;
  float v = 0.f;
  if(d<64){
    long base = (long)b*16384 + (long)m*64 + d;
    v = pW[base] + pW[base+65536] + pW[base+131072] + pW[base+196608];
  }
  zaT[i] = (f16)v;
}

// ---- F8: h = a1@zaT^T + conv(v) (f16 out, blk<128) | U = a3T@zb^T -----------
__global__ __launch_bounds__(256) void k_outh_U(const f16* __restrict__ a1, const f16* __restrict__ zaT,
    const float* __restrict__ vf, const float* __restrict__ wconv, f16* __restrict__ h,
    const f16* __restrict__ a3T, const f16* __restrict__ zb, f16* __restrict__ U){
  __shared__ f16 As[8192];
  __shared__ f16 Bs[8192];
  __shared__ float hs[8192];
  __shared__ float wc[33];
  int blk = blockIdx.x; int t = threadIdx.x;
  if(blk < 128){                        // h: [4096 x 64], K=256, + conv epilogue
    if(t<33) wc[t] = wconv[t];
    int bx = blk&31, b = blk>>5;
    int m0 = bx*128;
    // GEMM writes into LDS hs[128][64] (A pre-offset by m0 so rows are local)
    gemm_body(a1 + (long)b*1048576 + (long)m0*256, zaT + (long)b*32768, hs, 0,
              64, 256, 0, 0, 0, 4, nullptr, nullptr, As, Bs);
    __syncthreads();
    #pragma unroll
    for(int i=0;i<32;++i){
      int e = i*256+t; int d = e&63; int r = e>>6; int n = m0+r;
      float acc = hs[e];
      #pragma unroll
      for(int tau=0;tau<33;++tau){
        int nn = n + tau - 16;
        if(nn>=0 && nn<4096) acc += wc[tau]*vf[((long)b*4096+nn)*64 + d];
      }
      h[((long)b*4096+n)*64 + d] = (f16)acc;
    }
  } else {                              // U: [4096 x 256], K=256, f16 out
    int idx = blk-128;
    int bx = idx&31, by = (idx>>5)&1, b = idx>>6;
    gemm_body(a3T + (long)b*1048576, zb + (long)b*65536, U + (long)b*1048576, 1,
              256, 256, bx*128, by*128, 0, 4, nullptr, nullptr, As, Bs);
  }
}

// ---------------- F10: out0 = x + h@woutT^T + bout | attn = a1@U^T -----------
__global__ __launch_bounds__(256) void k_out_attn(const f16* __restrict__ h, const f16* __restrict__ woutT,
    const float* __restrict__ x, const float* __restrict__ bout, float* __restrict__ out0,
    const f16* __restrict__ a1, const f16* __restrict__ U, float* __restrict__ attn){
  __shared__ f16 As[8192];
  __shared__ f16 Bs[8192];
  int blk = blockIdx.x;
  if(blk < 512){                        // out0: [16384 x 512], K=64
    int bx = blk&127, by = blk>>7;
    gemm_body(h, woutT, out0, 0, 512, 64, bx*128, by*128, 0, 1, bout, x, As, Bs);
  } else {                              // attn: [4096 x 4096], K=256
    int idx = blk-512;
    int bx = idx&31, by = (idx>>5)&31, b = idx>>10;
    gemm_body(a1 + (long)b*1048576, U + (long)b*1048576, attn + (long)b*16777216, 0,
              4096, 256, bx*128, by*128, 0, 4, nullptr, nullptr, As, Bs);
  }
}

extern "C" void kernel_launch(void* const* d_in, const int* in_sizes, int n_in,
                              void* d_out, int out_size, void* d_ws, size_t ws_size,
                              hipStream_t stream) {
  (void)in_sizes; (void)n_in; (void)out_size; (void)ws_size;
  const float* x     = (const float*)d_in[0];
  const float* gamma = (const float*)d_in[1];
  const float* beta  = (const float*)d_in[2];
  const float* wqkv  = (const float*)d_in[3];
  const float* wout  = (const float*)d_in[4];
  const float* bout  = (const float*)d_in[5];
  const float* wconv = (const float*)d_in[6];

  char* ws = (char*)d_ws;
  f16*   xn   = (f16*)(ws + 0);
  float* s3   = (float*)(ws + 0);          // reuse after qkv gemm
  float* s1   = (float*)(ws + 16777216);
  f16*   a3T  = (f16*)(ws + 16777216);     // reuse after softmax1
  f16*   U    = (f16*)(ws + 25165824);
  float* qkv  = (float*)(ws + 33554432);
  f16*   a3   = (f16*)(ws + 33554432);     // reuse after split
  float* pY   = (float*)(ws + 33554432);   // y-pong: reuses dead a3/qkv region during pinv
  f16*   a1   = (f16*)(ws + 46137344);
  f16*   qf   = (f16*)(ws + 54525952);
  f16*   kf   = (f16*)(ws + 56623104);
  float* vf   = (float*)(ws + 58720256);
  f16*   vT   = (f16*)(ws + 62914560);
  f16*   wqkT = (f16*)(ws + 67108864);
  f16*   ql   = (f16*)(ws + 67371008);
  f16*   kl   = (f16*)(ws + 67502080);
  float* s2   = (float*)(ws + 67633152);
  float* a2   = (float*)(ws + 68681728);
  float* zA   = (float*)(ws + 69730304);   // combined z0 [4][256][256] (1 MB)
  f16*   zb   = (f16*)(ws + 74973184);
  float* rs   = (float*)(ws + 76021760);
  unsigned* csmax = (unsigned*)(ws + 76021760 + 4096);
  f16*   zaT  = (f16*)(ws + 76029952);     // [4][128][256] f16
  f16*   woutT= (f16*)(ws + 76292096);     // [512][64] f16
  f16*   h    = (f16*)(ws + 80551936);     // [16384][64] f16
  float* pXZ  = (float*)(ws + 82649088);   // 4 MB: y ping
  float* pT1  = (float*)(ws + 86843392);   // 4 MB: y2
  float* pT2  = (float*)(ws + 91037696);   // 4 MB: u
  float* pU0  = (float*)(ws + 95232000);   // 4 MB: z ping
  float* pU1  = (float*)(ws + 99426304);   // 4 MB: z pong
  float* a3vp = (float*)(ws + 103620608);  // [8][4][256][64] fp32 = 2 MB
  float* pW   = (float*)(ws + 105717760);  // [4][4][256][64] fp32 = 1 MB

  float* out0 = (float*)d_out;
  float* attn = out0 + 8388608;

  k_ln_prep<<<17025,256,0,stream>>>(x, gamma, beta, xn, wqkv, wout, wqkT, woutT, rs, csmax);
  k_qkv<<<256,256,0,stream>>>(xn, wqkT, qkv);
  k_splitvl<<<4608,256,0,stream>>>(qkv, qf, kf, vf, vT, ql, kl);
  k_sims<<<528,256,0,stream>>>(qf, kf, ql, kl, s1, s2, s3);
  k_softmaxes<<<6144,256,0,stream>>>(s1, a1, s2, a2, rs, csmax, s3, a3);
  k_trA3_a3v<<<1088,256,0,stream>>>(a3, a3T, vT, a3vp);
  // z0 (64 blk) + y0 = sc*a2@a2^T (256 blk, 4 slices -> pXZ), one launch
  k_z0y0<<<320,256,0,stream>>>(a2, rs, csmax, zA, pXZ);

  // Newton-Schulz, 6 iterations, 2 launches each:
  //   A: y2 = y@y -> pT1 ; u = z@y -> pT2
  //   B: z' = 3.25 z - 0.25 u@w2 ; y' = 3.25 y - 0.25 y2@w2  (w2 staged)
  float* yb = pXZ;  float* yp = pY;
  const float* zc = zA; int zAS = 1;
  for(int it=0; it<6; ++it){
    k_nsA<<<dim3(4,4,32),256,0,stream>>>(zc, zAS, yb, pT1, pT2);
    float* zn = (it&1) ? pU1 : pU0;
    if(it < 5){
      k_nsB<<<dim3(4,4,32),256,0,stream>>>(zc, zAS, yb, pT1, pT2, zn, yp);
      float* tmp = yb; yb = yp; yp = tmp;
    } else {
      k_nsB<<<dim3(4,4,16),256,0,stream>>>(zc, zAS, yb, pT1, pT2, zn, yp);
    }
    zc = zn; zAS = 4;
  }
  // zc = final z (4 slices, pU1)
  k_tail<<<192,256,0,stream>>>(zc, a3vp, pW, zb);
  k_trZ<<<512,256,0,stream>>>(pW, zaT);

  k_outh_U<<<384,256,0,stream>>>(a1, zaT, vf, wconv, h, a3T, zb, U);
  k_out_attn<<<4608,256,0,stream>>>(h, woutT, x, bout, out0, a1, U, attn);
}

// Round 10
// 707.052 us; speedup vs baseline: 2.1656x; 1.6536x over previous
//
#include <hip/hip_runtime.h>
#include <hip/hip_bf16.h>

// Nystromformer layer, MI355X. fp32 I/O, f16 MFMA internals, fp32 Newton-Schulz.
// R13 = R12 with ONE substantive fix: g256_body's diagonal insert used
//       `float* pv=&vb.x; pv[kglob-cbase]+=diagB` — a runtime-indexed vector
//       component, which forces vb into SCRATCH (rule: dyn-indexed vectors
//       alloca to local memory) in all 14 g256_body launches. R12 measured
//       1169us on a WARM node (node-state theory falsified; R8=752us), and
//       the ~420us regression is distributed across pinv launches — matching
//       the scratch mechanism. Fix: branchless ?: selects (v_cndmask, no
//       address taken).
// R9 lineage: pinv 2 launches/iter ({y2,u} / {z',y'} with w2-in-staging);
//       y0=sc*a2@a2^T fused with z0; conv fused into outh GEMM epilogue.
//       23 dispatches.

typedef _Float16 f16;
typedef f16 f16x2 __attribute__((ext_vector_type(2)));
typedef f16 f16x4 __attribute__((ext_vector_type(4)));
typedef f16 f16x8 __attribute__((ext_vector_type(8)));
typedef float f32x4 __attribute__((ext_vector_type(4)));

__device__ __forceinline__ float waveMax(float v){
  #pragma unroll
  for(int i=32;i>0;i>>=1) v = fmaxf(v, __shfl_xor(v, i));
  return v;
}
__device__ __forceinline__ float waveSum(float v){
  #pragma unroll
  for(int i=32;i>0;i>>=1) v += __shfl_xor(v, i);
  return v;
}
__device__ __forceinline__ float blockMaxF(float v, float* sm){
  v = waveMax(v);
  if((threadIdx.x&63)==0) sm[threadIdx.x>>6] = v;
  __syncthreads();
  v = fmaxf(fmaxf(sm[0],sm[1]), fmaxf(sm[2],sm[3]));
  __syncthreads();
  return v;
}
__device__ __forceinline__ float blockSumF(float v, float* sm){
  v = waveSum(v);
  if((threadIdx.x&63)==0) sm[threadIdx.x>>6] = v;
  __syncthreads();
  v = sm[0]+sm[1]+sm[2]+sm[3];
  __syncthreads();
  return v;
}

__device__ __forceinline__ void async_cp16(const f16* g, const f16* l){
  __builtin_amdgcn_global_load_lds((const __attribute__((address_space(1))) void*)g,
                                   (__attribute__((address_space(3))) void*)l, 16, 0, 0);
}

// ---------------- MFMA GEMM body: C[M][N] = A[M][K] * Bt[N][K]^T -------------
// 128x128 tile, BK=64, 4 waves, 16x16x32 f16 MFMA.
__device__ __forceinline__ void gemm_body(
    const f16* __restrict__ A, const f16* __restrict__ Bt, void* __restrict__ C, int cf16,
    int N, int K, int m0, int n0, int kt0, int ktn,
    const float* __restrict__ bias, const float* __restrict__ resid,
    f16* As, f16* Bs)
{
  int t = threadIdx.x;
  int w = t>>6, lane = t&63;
  int quad = lane>>4, l16 = lane&15;
  int wr = w>>1, wc = w&1;
  f32x4 acc[4][4] = {};
  for(int kt=kt0; kt<kt0+ktn; ++kt){
    #pragma unroll
    for(int i=0;i<4;++i){
      int G = (w<<8)+(i<<6)+lane;
      int row = G>>3, gs = G&7;
      int g = gs ^ (row&7);                       // XOR-swizzled granule
      int koff = (kt<<6)+(g<<3);
      async_cp16(A + (long)(m0+row)*K + koff, As + (((w<<8)+(i<<6))<<3));
      async_cp16(Bt + (long)(n0+row)*K + koff, Bs + (((w<<8)+(i<<6))<<3));
    }
    __syncthreads();
    #pragma unroll
    for(int kk=0; kk<2; ++kk){
      f16x8 af[4], bfr[4];
      int gb = (kk<<2) + quad;
      #pragma unroll
      for(int mi=0;mi<4;++mi){
        int row = (wr<<6)+(mi<<4)+l16;
        af[mi] = *(const f16x8*)(As + ((row<<6) + ((gb ^ (row&7))<<3)));
      }
      #pragma unroll
      for(int ni=0;ni<4;++ni){
        int row = (wc<<6)+(ni<<4)+l16;
        bfr[ni] = *(const f16x8*)(Bs + ((row<<6) + ((gb ^ (row&7))<<3)));
      }
      #pragma unroll
      for(int mi=0;mi<4;++mi){
        #pragma unroll
        for(int ni=0;ni<4;++ni)
          acc[mi][ni] = __builtin_amdgcn_mfma_f32_16x16x32_f16(af[mi], bfr[ni], acc[mi][ni], 0,0,0);
      }
    }
    __syncthreads();
  }
  #pragma unroll
  for(int mi=0;mi<4;++mi){
    int rowb = m0 + (wr<<6) + (mi<<4) + (quad<<2);
    #pragma unroll
    for(int ni=0;ni<4;++ni){
      int col = n0 + (wc<<6) + (ni<<4) + l16;
      if(col < N){
        #pragma unroll
        for(int r=0;r<4;++r){
          float v = acc[mi][ni][r];
          if(bias)  v += bias[col];
          if(resid) v += resid[(long)(rowb+r)*N + col];
          if(cf16) ((f16*)C)[(long)(rowb+r)*N + col] = (f16)v;
          else     ((float*)C)[(long)(rowb+r)*N + col] = v;
        }
      }
    }
  }
}

// ------- fp32 GEMM body, split-K x4, partial-slice I/O (pinv chain) ----------
// Block computes beta*(A@Bv) over K-slice [ks*64,ks*64+64) of 64x64 tile of
// batch b; stores to slice ks of D. Bv = sum(B slices) + cB2*sum(B2 slices)
// + diagB*I (the w2-in-staging trick). ks==0 adds alpha*sum(E slices) + diagv*I.
// A,E,B2 slice stride 262144; B,D slice stride 4*256*Ncols.
__device__ __forceinline__ void g256_body(const float* __restrict__ A, const float* __restrict__ B,
    const float* __restrict__ B2, float cB2, float diagB,
    const float* __restrict__ E, float* __restrict__ D, int Ncols, float beta, float alpha,
    int AS, int BS, int ES, int bx, int by, int b, int ks, float* At, float* Bss, float diagv)
{
  long aOff = (long)b*65536;
  long bBatch = 256L*Ncols, bSl = 4L*bBatch;
  long bOff = (long)b*bBatch;
  long dOff = (long)ks*bSl + bOff;
  int r0 = bx*64, c0 = by*64;
  int t = threadIdx.x, tr = t>>4, tc = t&15;
  int arow = t>>2, ac4 = t&3;
  int bk = t>>4, bn4 = t&15;
  float acc[4][4] = {};
  for(int k0=ks*64;k0<ks*64+64;k0+=16){
    const float* pa = A + aOff + (long)(r0+arow)*256 + k0 + ac4*4;
    float4 va = *(const float4*)pa;
    for(int s=1;s<AS;++s){ float4 w2 = *(const float4*)(pa + (long)s*262144);
      va.x+=w2.x; va.y+=w2.y; va.z+=w2.z; va.w+=w2.w; }
    At[(ac4*4+0)*72+arow]=va.x; At[(ac4*4+1)*72+arow]=va.y;
    At[(ac4*4+2)*72+arow]=va.z; At[(ac4*4+3)*72+arow]=va.w;
    const float* pb = B + bOff + (long)(k0+bk)*Ncols + c0 + bn4*4;
    float4 vb = *(const float4*)pb;
    for(int s=1;s<BS;++s){ float4 w2 = *(const float4*)(pb + (long)s*bSl);
      vb.x+=w2.x; vb.y+=w2.y; vb.z+=w2.z; vb.w+=w2.w; }
    if(B2){
      const float* pb2 = B2 + (long)b*65536 + (long)(k0+bk)*256 + c0 + bn4*4;
      float s2x=0.f,s2y=0.f,s2z=0.f,s2w=0.f;
      for(int s=0;s<4;++s){ float4 w2 = *(const float4*)(pb2 + (long)s*262144);
        s2x+=w2.x; s2y+=w2.y; s2z+=w2.z; s2w+=w2.w; }
      vb.x+=cB2*s2x; vb.y+=cB2*s2y; vb.z+=cB2*s2z; vb.w+=cB2*s2w;
    }
    if(diagB != 0.f){
      // R13 FIX: branchless selects instead of `float* pv=&vb.x; pv[idx]+=`.
      // The runtime-indexed component forced vb into scratch (local memory)
      // in every g256_body launch — ~420us distributed regression.
      int kglob = k0 + bk, cbase = c0 + bn4*4;
      vb.x += (kglob==cbase  ) ? diagB : 0.f;
      vb.y += (kglob==cbase+1) ? diagB : 0.f;
      vb.z += (kglob==cbase+2) ? diagB : 0.f;
      vb.w += (kglob==cbase+3) ? diagB : 0.f;
    }
    *(float4*)&Bss[bk*72+bn4*4] = vb;
    __syncthreads();
    #pragma unroll
    for(int kk=0;kk<16;++kk){
      float4 a4 = *(const float4*)&At[kk*72+tr*4];
      float4 b4 = *(const float4*)&Bss[kk*72+tc*4];
      float av[4] = {a4.x,a4.y,a4.z,a4.w};
      float bv[4] = {b4.x,b4.y,b4.z,b4.w};
      #pragma unroll
      for(int i=0;i<4;++i){
        #pragma unroll
        for(int j=0;j<4;++j) acc[i][j] += av[i]*bv[j];
      }
    }
    __syncthreads();
  }
  #pragma unroll
  for(int i=0;i<4;++i){
    int row = r0 + tr*4 + i;
    #pragma unroll
    for(int j=0;j<4;++j){
      int col = c0 + tc*4 + j;
      float v = beta*acc[i][j];
      if(ks==0){
        if(ES>0){
          const float* pe = E + aOff + (long)row*256 + col;
          float e = pe[0];
          for(int s=1;s<ES;++s) e += pe[(long)s*262144];
          v += alpha*e;
        }
        if(row==col) v += diagv;
      }
      D[dOff + (long)row*Ncols + col] = v;
    }
  }
}

// ---- y0 = sc * a2 @ a2^T (B staged A-style from a2 rows; symmetric) ---------
// Slice layout matches g256_body: slice stride 262144 ELEMENTS, batch 65536.
__device__ __forceinline__ void g256_aat(const float* __restrict__ A, float* __restrict__ D,
    float sc, int bx, int by, int b, int ks, float* At, float* Bss)
{
  long aOff = (long)b*65536;
  long dOff = (long)ks*262144 + (long)b*65536;
  int r0 = bx*64, c0 = by*64;
  int t = threadIdx.x, tr = t>>4, tc = t&15;
  int arow = t>>2, ac4 = t&3;
  float acc[4][4] = {};
  for(int k0=ks*64;k0<ks*64+64;k0+=16){
    float4 va = *(const float4*)(A + aOff + (long)(r0+arow)*256 + k0 + ac4*4);
    At[(ac4*4+0)*72+arow]=va.x; At[(ac4*4+1)*72+arow]=va.y;
    At[(ac4*4+2)*72+arow]=va.z; At[(ac4*4+3)*72+arow]=va.w;
    float4 vb = *(const float4*)(A + aOff + (long)(c0+arow)*256 + k0 + ac4*4);
    Bss[(ac4*4+0)*72+arow]=vb.x; Bss[(ac4*4+1)*72+arow]=vb.y;
    Bss[(ac4*4+2)*72+arow]=vb.z; Bss[(ac4*4+3)*72+arow]=vb.w;
    __syncthreads();
    #pragma unroll
    for(int kk=0;kk<16;++kk){
      float4 a4 = *(const float4*)&At[kk*72+tr*4];
      float4 b4 = *(const float4*)&Bss[kk*72+tc*4];
      float av[4] = {a4.x,a4.y,a4.z,a4.w};
      float bv[4] = {b4.x,b4.y,b4.z,b4.w};
      #pragma unroll
      for(int i=0;i<4;++i){
        #pragma unroll
        for(int j=0;j<4;++j) acc[i][j] += av[i]*bv[j];
      }
    }
    __syncthreads();
  }
  #pragma unroll
  for(int i=0;i<4;++i){
    int row = r0 + tr*4 + i;
    #pragma unroll
    for(int j=0;j<4;++j){
      int col = c0 + tc*4 + j;
      D[dOff + (long)row*256 + col] = sc*acc[i][j];
    }
  }
}

// ---------------- F1: LayerNorm + weight transposes + zero scratch -----------
__global__ __launch_bounds__(256) void k_ln_prep(const float* __restrict__ x, const float* __restrict__ g,
    const float* __restrict__ be, f16* __restrict__ xn, const float* __restrict__ wqkv,
    const float* __restrict__ wout, f16* __restrict__ wqkT, f16* __restrict__ woutT,
    float* __restrict__ rs, unsigned* __restrict__ csmax){
  __shared__ float sm[8];
  int blk = blockIdx.x; int t = threadIdx.x;
  if(blk < 16384){
    long row = blk;
    const float* xr = x + row*512;
    float v0 = xr[t], v1 = xr[t+256];
    float s = waveSum(v0+v1), ss = waveSum(v0*v0+v1*v1);
    if((t&63)==0){ sm[t>>6] = s; sm[(t>>6)+4] = ss; }
    __syncthreads();
    s = sm[0]+sm[1]+sm[2]+sm[3]; ss = sm[4]+sm[5]+sm[6]+sm[7];
    float mu = s*(1.f/512.f);
    float var = ss*(1.f/512.f) - mu*mu;
    float rstd = rsqrtf(var + 1e-5f);
    xn[row*512+t]     = (f16)((v0-mu)*rstd*g[t]     + be[t]);
    xn[row*512+t+256] = (f16)((v1-mu)*rstd*g[t+256] + be[t+256]);
  } else if(blk < 16896){
    int i = (blk-16384)*256 + t; int n = i>>9, k = i&511;
    wqkT[i] = (n<192) ? (f16)wqkv[k*192+n] : (f16)0.0f;
  } else if(blk < 17024){
    int i = (blk-16896)*256 + t; int n = i>>6, k = i&63;
    woutT[i] = (f16)wout[k*512+n];
  } else {
    rs[t]=0.f; rs[t+256]=0.f; rs[t+512]=0.f; rs[t+768]=0.f;
    if(t==0){ *csmax = 0u; }
  }
}

// ---------------- F2: qkv = xn @ wqkT^T --------------------------------------
__global__ __launch_bounds__(256) void k_qkv(const f16* __restrict__ xn, const f16* __restrict__ wqkT,
                                             float* __restrict__ qkv){
  __shared__ f16 As[8192];
  __shared__ f16 Bs[8192];
  int blk = blockIdx.x;                 // 256 = (128 m) x (2 n)
  int bx = blk&127, by = blk>>7;
  gemm_body(xn, wqkT, qkv, 0, 192, 512, bx*128, by*128, 0, 8, nullptr, nullptr, As, Bs);
}

// ---------------- F3: split + vT + landmarks (all read qkv) ------------------
__global__ __launch_bounds__(256) void k_splitvl(const float* __restrict__ qkv,
    f16* __restrict__ qf, f16* __restrict__ kf, float* __restrict__ vf,
    f16* __restrict__ vT, f16* __restrict__ ql, f16* __restrict__ kl){
  __shared__ float tile[64][65];
  int blk = blockIdx.x; int t = threadIdx.x;
  if(blk < 4096){
    long row = (long)blk*4 + (t>>6); int d = t&63;
    const float* p = qkv + row*192;
    qf[row*64+d] = (f16)(p[d]*0.125f);
    kf[row*64+d] = (f16)(p[d+64]);
    vf[row*64+d] = p[d+128];
  } else if(blk < 4352){
    int bidx = blk-4096; int b = bidx>>6, n0 = (bidx&63)*64;
    int c = t&63, r4 = t>>6;
    #pragma unroll
    for(int i=0;i<16;++i){ int r = i*4+r4;
      tile[r][c] = qkv[((long)(b*4096 + n0 + r))*192 + 128 + c]; }
    __syncthreads();
    #pragma unroll
    for(int i=0;i<16;++i){ int d = i*4+r4;
      vT[((long)(b*128 + d))*4096 + n0 + c] = (f16)tile[c][d]; }
  } else {
    int bidx = blk-4352;                 // 256 blocks
    int bm = bidx*4 + (t>>6); int d = t&63;   // bm in [0,1024)
    const float* p = qkv + (long)bm*16*192;
    float sq=0.f, sk=0.f;
    #pragma unroll
    for(int i=0;i<16;++i){ sq += p[i*192+d]; sk += p[i*192+64+d]; }
    ql[bm*64+d] = (f16)(sq*0.0625f*0.125f);
    kl[bm*64+d] = (f16)(sk*0.0625f);
  }
}

// ---------------- F4: sims s1 | s2 | s3 --------------------------------------
__global__ __launch_bounds__(256) void k_sims(const f16* __restrict__ qf, const f16* __restrict__ kf,
    const f16* __restrict__ ql, const f16* __restrict__ kl,
    float* __restrict__ s1, float* __restrict__ s2, float* __restrict__ s3){
  __shared__ f16 As[8192];
  __shared__ f16 Bs[8192];
  int blk = blockIdx.x;
  if(blk < 256){                        // s1 = q @ kl^T : [4096 x 256], K=64
    int bx = blk&31, by = (blk>>5)&1, b = blk>>6;
    gemm_body(qf + (long)b*262144, kl + (long)b*16384, s1 + (long)b*1048576, 0,
              256, 64, bx*128, by*128, 0, 1, nullptr, nullptr, As, Bs);
  } else if(blk < 272){                 // s2 = ql @ kl^T : [256 x 256], K=64
    int idx = blk-256;
    int bx = idx&1, by = (idx>>1)&1, b = idx>>2;
    gemm_body(ql + (long)b*16384, kl + (long)b*16384, s2 + (long)b*65536, 0,
              256, 64, bx*128, by*128, 0, 1, nullptr, nullptr, As, Bs);
  } else {                              // s3 = ql @ k^T : [256 x 4096], K=64
    int idx = blk-272;
    int bx = idx&1, by = (idx>>1)&31, b = idx>>6;
    gemm_body(ql + (long)b*16384, kf + (long)b*262144, s3 + (long)b*1048576, 0,
              4096, 64, bx*128, by*128, 0, 1, nullptr, nullptr, As, Bs);
  }
}

// ---------------- F5: softmax1 | softmax2 | softmax3 -------------------------
__global__ __launch_bounds__(256) void k_softmaxes(const float* __restrict__ s1, f16* __restrict__ a1,
    const float* __restrict__ s2, float* __restrict__ a2, float* __restrict__ rs, unsigned* __restrict__ csmax,
    const float* __restrict__ s3, f16* __restrict__ a3){
  __shared__ float sm[4];
  int blk = blockIdx.x; int t = threadIdx.x;
  if(blk < 4096){
    int w = t>>6, lane = t&63;
    long row = (long)blk*4 + w;
    float4 v = *(const float4*)(s1 + row*256 + lane*4);
    float m = waveMax(fmaxf(fmaxf(v.x,v.y),fmaxf(v.z,v.w)));
    float e0 = __expf(v.x-m), e1 = __expf(v.y-m), e2 = __expf(v.z-m), e3 = __expf(v.w-m);
    float inv = 1.f/waveSum(e0+e1+e2+e3);
    f16x4 o = {(f16)(e0*inv),(f16)(e1*inv),(f16)(e2*inv),(f16)(e3*inv)};
    *(f16x4*)(a1 + row*256 + lane*4) = o;
  } else if(blk < 5120){
    int row = blk-4096; int b = row>>8;
    float v = s2[row*256+t];
    float m = blockMaxF(v, sm);
    float e = __expf(v-m);
    float sum = blockSumF(e, sm);
    float p = e/sum;
    a2[(long)row*256+t] = p;
    atomicAdd(&rs[b*256+t], p);
    float rowsum = blockSumF(p, sm);
    if(t==0) atomicMax(csmax, __float_as_uint(rowsum));
  } else {
    long row = blk-5120;
    const float* p = s3 + row*4096;
    float4 v[4]; float m = -1e30f;
    #pragma unroll
    for(int i=0;i<4;++i){
      v[i] = *(const float4*)(p + (i*256+t)*4);
      m = fmaxf(m, fmaxf(fmaxf(v[i].x,v[i].y),fmaxf(v[i].z,v[i].w)));
    }
    m = blockMaxF(m, sm);
    float sum = 0.f;
    #pragma unroll
    for(int i=0;i<4;++i){
      v[i].x = __expf(v[i].x-m); v[i].y = __expf(v[i].y-m);
      v[i].z = __expf(v[i].z-m); v[i].w = __expf(v[i].w-m);
      sum += v[i].x+v[i].y+v[i].z+v[i].w;
    }
    float inv = 1.f/blockSumF(sum, sm);
    f16* o = a3 + row*4096;
    #pragma unroll
    for(int i=0;i<4;++i){
      f16x4 ov = {(f16)(v[i].x*inv),(f16)(v[i].y*inv),(f16)(v[i].z*inv),(f16)(v[i].w*inv)};
      *(f16x4*)(o + (i*256+t)*4) = ov;
    }
  }
}

// ---------------- F6: trA3 | a3v split-K x8 ----------------------------------
__global__ __launch_bounds__(256) void k_trA3_a3v(const f16* __restrict__ a3, f16* __restrict__ a3T,
    const f16* __restrict__ vT, float* __restrict__ a3vp){
  __shared__ f16 As[8192];
  __shared__ f16 Bs[8192];
  __shared__ f16 tile[64][74];
  int blk = blockIdx.x; int t = threadIdx.x;
  if(blk < 1024){
    int bx = blk&63, by = (blk>>6)&3, b = blk>>8;
    int n0 = bx*64, m0 = by*64;
    const f16* A = a3 + (long)b*1048576; f16* T = a3T + (long)b*1048576;
    int c = t&63, r4 = t>>6;
    #pragma unroll
    for(int i=0;i<16;++i){ int r = i*4+r4; tile[r][c] = A[(long)(m0+r)*4096 + n0 + c]; }
    __syncthreads();
    #pragma unroll
    for(int i=0;i<16;++i){ int nr = i*4+r4; T[(long)(n0+nr)*256 + m0 + c] = tile[c][nr]; }
  } else {
    int idx = blk-1024;                 // 64 blocks: (2 m) x (32 z)
    int bx = idx&1, zz = idx>>1;
    int b = zz>>3, ksl = zz&7;
    gemm_body(a3 + (long)b*1048576, vT + (long)b*524288,
              a3vp + (long)ksl*65536 + (long)b*16384, 0,
              64, 4096, bx*128, 0, ksl*8, 8, nullptr, nullptr, As, Bs);
  }
}

// ---------------- F7: z0 = sc*a2^T (64 blk) | y0 = sc*a2@a2^T (256 blk) ------
__global__ __launch_bounds__(256) void k_z0y0(const float* __restrict__ a2, const float* __restrict__ rs,
    const unsigned* __restrict__ csmax, float* __restrict__ zA, float* __restrict__ y0){
  __shared__ float sm4[4];
  __shared__ float At[1152];
  __shared__ float Bss[1152];
  __shared__ float tile[64][65];
  int blk = blockIdx.x; int t = threadIdx.x;
  float m = fmaxf(fmaxf(rs[t],rs[t+256]), fmaxf(rs[t+512],rs[t+768]));
  m = blockMaxF(m, sm4);
  float sc = 1.f/(__uint_as_float(*csmax)*m);
  if(blk < 64){
    int ix = blk&3, jy = (blk>>2)&3, b = blk>>4;
    int i0 = ix*64, j0 = jy*64;
    const float* A = a2 + (long)b*65536; float* Z = zA + (long)b*65536;
    int c = t&63, r4 = t>>6;
    #pragma unroll
    for(int i=0;i<16;++i){ int r = i*4+r4; tile[r][c] = A[(j0+r)*256 + i0 + c]; }
    __syncthreads();
    #pragma unroll
    for(int i=0;i<16;++i){ int r = i*4+r4; Z[(i0+r)*256 + j0 + c] = tile[c][r]*sc; }
  } else {
    int idx = blk-64;
    int bx = idx&3, by = (idx>>2)&3, b = (idx>>4)&3, ks = idx>>6;
    g256_aat(a2, y0, sc, bx, by, b, ks, At, Bss);
  }
}

// ---------------- pinv launch A: y2 = y@y | u = zc@y (grid 4,4,32) -----------
__global__ __launch_bounds__(256) void k_nsA(const float* __restrict__ zc, int zAS,
    const float* __restrict__ y, float* __restrict__ y2, float* __restrict__ u){
  __shared__ float At[1152];
  __shared__ float Bss[1152];
  int z = blockIdx.z;
  if(z < 16){
    int b = z&3, ks = z>>2;
    g256_body(y, y, nullptr, 0.f, 0.f, nullptr, y2, 256, 1.f, 0.f, 4, 4, 0,
              blockIdx.x, blockIdx.y, b, ks, At, Bss, 0.f);
  } else {
    int zz = z-16; int b = zz&3, ks = zz>>2;
    g256_body(zc, y, nullptr, 0.f, 0.f, nullptr, u, 256, 1.f, 0.f, zAS, 4, 0,
              blockIdx.x, blockIdx.y, b, ks, At, Bss, 0.f);
  }
}

// ---- pinv launch B: z' = 3.25 zc - 0.25 u@w2 | y' = 3.25 y - 0.25 y2@w2 -----
// w2 = sum(y2) - 7 sum(y) + 15I formed during B-staging.
__global__ __launch_bounds__(256) void k_nsB(const float* __restrict__ zc, int zAS,
    const float* __restrict__ y, const float* __restrict__ y2, const float* __restrict__ u,
    float* __restrict__ zn, float* __restrict__ yn){
  __shared__ float At[1152];
  __shared__ float Bss[1152];
  int z = blockIdx.z;
  if(z < 16){
    int b = z&3, ks = z>>2;
    g256_body(u, y2, y, -7.f, 15.f, zc, zn, 256, -0.25f, 3.25f, 4, 4, zAS,
              blockIdx.x, blockIdx.y, b, ks, At, Bss, 0.f);
  } else {
    int zz = z-16; int b = zz&3, ks = zz>>2;
    g256_body(y2, y2, y, -7.f, 15.f, y, yn, 256, -0.25f, 3.25f, 4, 4, 4,
              blockIdx.x, blockIdx.y, b, ks, At, Bss, 0.f);
  }
}

// ---------------- pinv tail: za3v GEMM (64 blk) | zb combine (128 blk) -------
__global__ __launch_bounds__(256) void k_tail(const float* __restrict__ zc, const float* __restrict__ a3vp,
    float* __restrict__ pW, f16* __restrict__ zb){
  __shared__ float At[1152];
  __shared__ float Bss[1152];
  int blk = blockIdx.x; int t = threadIdx.x;
  if(blk < 64){
    int zx = blk&3, zz = blk>>2;
    int b = zz&3, ks = zz>>2;
    g256_body(zc, a3vp, nullptr, 0.f, 0.f, nullptr, pW, 64, 1.f, 0.f, 4, 8, 0,
              zx, 0, b, ks, At, Bss, 0.f);
  } else if(blk < 192){
    int base = (blk-64)*2048;
    #pragma unroll
    for(int k=0;k<8;++k){
      int i = base + k*256 + t;
      float v = zc[i] + zc[i+262144] + zc[i+524288] + zc[i+786432];
      zb[i] = (f16)v;
    }
  }
}

// ---- pW partials (4 slices of [4][256][64]) -> zaT f16 [4][128pad][256] -----
__global__ __launch_bounds__(256) void k_trZ(const float* __restrict__ pW, f16* __restrict__ zaT){
  int i = blockIdx.x*256 + threadIdx.x;   // 131072
  int b = i>>15, j = i&32767; int d = j>>8, m = j&255;
  float v = 0.f;
  if(d<64){
    long base = (long)b*16384 + (long)m*64 + d;
    v = pW[base] + pW[base+65536] + pW[base+131072] + pW[base+196608];
  }
  zaT[i] = (f16)v;
}

// ---- F8: h = a1@zaT^T + conv(v) (f16 out, blk<128) | U = a3T@zb^T -----------
__global__ __launch_bounds__(256) void k_outh_U(const f16* __restrict__ a1, const f16* __restrict__ zaT,
    const float* __restrict__ vf, const float* __restrict__ wconv, f16* __restrict__ h,
    const f16* __restrict__ a3T, const f16* __restrict__ zb, f16* __restrict__ U){
  __shared__ f16 As[8192];
  __shared__ f16 Bs[8192];
  __shared__ float hs[8192];
  __shared__ float wc[33];
  int blk = blockIdx.x; int t = threadIdx.x;
  if(blk < 128){                        // h: [4096 x 64], K=256, + conv epilogue
    if(t<33) wc[t] = wconv[t];
    int bx = blk&31, b = blk>>5;
    int m0 = bx*128;
    // GEMM writes into LDS hs[128][64] (A pre-offset by m0 so rows are local)
    gemm_body(a1 + (long)b*1048576 + (long)m0*256, zaT + (long)b*32768, hs, 0,
              64, 256, 0, 0, 0, 4, nullptr, nullptr, As, Bs);
    __syncthreads();
    #pragma unroll
    for(int i=0;i<32;++i){
      int e = i*256+t; int d = e&63; int r = e>>6; int n = m0+r;
      float acc = hs[e];
      #pragma unroll
      for(int tau=0;tau<33;++tau){
        int nn = n + tau - 16;
        if(nn>=0 && nn<4096) acc += wc[tau]*vf[((long)b*4096+nn)*64 + d];
      }
      h[((long)b*4096+n)*64 + d] = (f16)acc;
    }
  } else {                              // U: [4096 x 256], K=256, f16 out
    int idx = blk-128;
    int bx = idx&31, by = (idx>>5)&1, b = idx>>6;
    gemm_body(a3T + (long)b*1048576, zb + (long)b*65536, U + (long)b*1048576, 1,
              256, 256, bx*128, by*128, 0, 4, nullptr, nullptr, As, Bs);
  }
}

// ---------------- F10: out0 = x + h@woutT^T + bout | attn = a1@U^T -----------
__global__ __launch_bounds__(256) void k_out_attn(const f16* __restrict__ h, const f16* __restrict__ woutT,
    const float* __restrict__ x, const float* __restrict__ bout, float* __restrict__ out0,
    const f16* __restrict__ a1, const f16* __restrict__ U, float* __restrict__ attn){
  __shared__ f16 As[8192];
  __shared__ f16 Bs[8192];
  int blk = blockIdx.x;
  if(blk < 512){                        // out0: [16384 x 512], K=64
    int bx = blk&127, by = blk>>7;
    gemm_body(h, woutT, out0, 0, 512, 64, bx*128, by*128, 0, 1, bout, x, As, Bs);
  } else {                              // attn: [4096 x 4096], K=256
    int idx = blk-512;
    int bx = idx&31, by = (idx>>5)&31, b = idx>>10;
    gemm_body(a1 + (long)b*1048576, U + (long)b*1048576, attn + (long)b*16777216, 0,
              4096, 256, bx*128, by*128, 0, 4, nullptr, nullptr, As, Bs);
  }
}

extern "C" void kernel_launch(void* const* d_in, const int* in_sizes, int n_in,
                              void* d_out, int out_size, void* d_ws, size_t ws_size,
                              hipStream_t stream) {
  (void)in_sizes; (void)n_in; (void)out_size; (void)ws_size;
  const float* x     = (const float*)d_in[0];
  const float* gamma = (const float*)d_in[1];
  const float* beta  = (const float*)d_in[2];
  const float* wqkv  = (const float*)d_in[3];
  const float* wout  = (const float*)d_in[4];
  const float* bout  = (const float*)d_in[5];
  const float* wconv = (const float*)d_in[6];

  char* ws = (char*)d_ws;
  f16*   xn   = (f16*)(ws + 0);
  float* s3   = (float*)(ws + 0);          // reuse after qkv gemm
  float* s1   = (float*)(ws + 16777216);
  f16*   a3T  = (f16*)(ws + 16777216);     // reuse after softmax1
  f16*   U    = (f16*)(ws + 25165824);
  float* qkv  = (float*)(ws + 33554432);
  f16*   a3   = (f16*)(ws + 33554432);     // reuse after split
  float* pY   = (float*)(ws + 33554432);   // y-pong: reuses dead a3/qkv region during pinv
  f16*   a1   = (f16*)(ws + 46137344);
  f16*   qf   = (f16*)(ws + 54525952);
  f16*   kf   = (f16*)(ws + 56623104);
  float* vf   = (float*)(ws + 58720256);
  f16*   vT   = (f16*)(ws + 62914560);
  f16*   wqkT = (f16*)(ws + 67108864);
  f16*   ql   = (f16*)(ws + 67371008);
  f16*   kl   = (f16*)(ws + 67502080);
  float* s2   = (float*)(ws + 67633152);
  float* a2   = (float*)(ws + 68681728);
  float* zA   = (float*)(ws + 69730304);   // combined z0 [4][256][256] (1 MB)
  f16*   zb   = (f16*)(ws + 74973184);
  float* rs   = (float*)(ws + 76021760);
  unsigned* csmax = (unsigned*)(ws + 76021760 + 4096);
  f16*   zaT  = (f16*)(ws + 76029952);     // [4][128][256] f16
  f16*   woutT= (f16*)(ws + 76292096);     // [512][64] f16
  f16*   h    = (f16*)(ws + 80551936);     // [16384][64] f16
  float* pXZ  = (float*)(ws + 82649088);   // 4 MB: y ping
  float* pT1  = (float*)(ws + 86843392);   // 4 MB: y2
  float* pT2  = (float*)(ws + 91037696);   // 4 MB: u
  float* pU0  = (float*)(ws + 95232000);   // 4 MB: z ping
  float* pU1  = (float*)(ws + 99426304);   // 4 MB: z pong
  float* a3vp = (float*)(ws + 103620608);  // [8][4][256][64] fp32 = 2 MB
  float* pW   = (float*)(ws + 105717760);  // [4][4][256][64] fp32 = 1 MB

  float* out0 = (float*)d_out;
  float* attn = out0 + 8388608;

  k_ln_prep<<<17025,256,0,stream>>>(x, gamma, beta, xn, wqkv, wout, wqkT, woutT, rs, csmax);
  k_qkv<<<256,256,0,stream>>>(xn, wqkT, qkv);
  k_splitvl<<<4608,256,0,stream>>>(qkv, qf, kf, vf, vT, ql, kl);
  k_sims<<<528,256,0,stream>>>(qf, kf, ql, kl, s1, s2, s3);
  k_softmaxes<<<6144,256,0,stream>>>(s1, a1, s2, a2, rs, csmax, s3, a3);
  k_trA3_a3v<<<1088,256,0,stream>>>(a3, a3T, vT, a3vp);
  // z0 (64 blk) + y0 = sc*a2@a2^T (256 blk, 4 slices -> pXZ), one launch
  k_z0y0<<<320,256,0,stream>>>(a2, rs, csmax, zA, pXZ);

  // Newton-Schulz, 6 iterations, 2 launches each:
  //   A: y2 = y@y -> pT1 ; u = z@y -> pT2
  //   B: z' = 3.25 z - 0.25 u@w2 ; y' = 3.25 y - 0.25 y2@w2  (w2 staged)
  float* yb = pXZ;  float* yp = pY;
  const float* zc = zA; int zAS = 1;
  for(int it=0; it<6; ++it){
    k_nsA<<<dim3(4,4,32),256,0,stream>>>(zc, zAS, yb, pT1, pT2);
    float* zn = (it&1) ? pU1 : pU0;
    if(it < 5){
      k_nsB<<<dim3(4,4,32),256,0,stream>>>(zc, zAS, yb, pT1, pT2, zn, yp);
      float* tmp = yb; yb = yp; yp = tmp;
    } else {
      k_nsB<<<dim3(4,4,16),256,0,stream>>>(zc, zAS, yb, pT1, pT2, zn, yp);
    }
    zc = zn; zAS = 4;
  }
  // zc = final z (4 slices, pU1)
  k_tail<<<192,256,0,stream>>>(zc, a3vp, pW, zb);
  k_trZ<<<512,256,0,stream>>>(pW, zaT);

  k_outh_U<<<384,256,0,stream>>>(a1, zaT, vf, wconv, h, a3T, zb, U);
  k_out_attn<<<4608,256,0,stream>>>(h, woutT, x, bout, out0, a1, U, attn);
}